// Round 2
// baseline (296.880 us; speedup 1.0000x reference)
//
#include <hip/hip_runtime.h>

#define B_  4
#define C1  256
#define C2  128
#define HH  64
#define WW  64
#define H2  128
#define W2  128

using short8  = __attribute__((ext_vector_type(8))) short;
using floatx4 = __attribute__((ext_vector_type(4))) float;
typedef unsigned short ushort_t;

// ---- workspace layout (bytes) ----
#define W1C_OFF 0u                                   // [cls4][tap4][co128][ci256] bf16
#define W1C_ELEMS (4 * 4 * 128 * 256)
#define W2C_OFF (W1C_ELEMS * 2u)                     // [tap9][o128][ci128] bf16
#define W2C_ELEMS (9 * 128 * 128)
#define KG_OFF  (W2C_OFF + W2C_ELEMS * 2u)           // [b][h][tap9][w128] fp32
#define KG_ELEMS (B_ * H2 * 9 * W2)
#define XT_OFF  (KG_OFF + KG_ELEMS * 4u)             // x -> [b][ih][iw][ci] bf16
#define XT_ELEMS (B_ * HH * WW * C1)
#define Y_OFF   (XT_OFF + XT_ELEMS * 2u)             // y -> [b][h][w][c] bf16
#define Y_ELEMS (B_ * H2 * W2 * C2)

static __device__ __forceinline__ ushort_t f2bf(float f) {
    union { float f; unsigned u; } v; v.f = f;
    unsigned r = v.u + 0x7FFFu + ((v.u >> 16) & 1u);   // RNE
    return (ushort_t)(r >> 16);
}

// ---------------------------------------------------------------------------
// Prep: w1 -> w1c[cls][tap][co][ci] bf16 (cls=p*2+pw', tap=th*2+tw)
// ---------------------------------------------------------------------------
__global__ void w1c_kernel(const float* __restrict__ w1, ushort_t* __restrict__ w1c) {
    int i = blockIdx.x * 256 + threadIdx.x;
    const int ci  = i & 255;
    const int co  = (i >> 8) & 127;
    const int tap = (i >> 15) & 3;
    const int cls = i >> 17;
    const int kh  = (cls >> 1) + 2 * (tap >> 1);
    const int kw  = (cls & 1) + 2 * (tap & 1);
    w1c[i] = f2bf(w1[((ci * C2 + co) * 4 + kh) * 4 + kw]);
}

// w2 -> w2c[tap][o][ci] bf16 with flip baked in
__global__ void w2c_kernel(const float* __restrict__ w2, ushort_t* __restrict__ w2c) {
    int i = blockIdx.x * 256 + threadIdx.x;
    const int ci  = i & 127;
    const int o   = (i >> 7) & 127;
    const int tap = i >> 14;
    const int fi  = 2 - tap / 3;
    const int fj  = 2 - tap % 3;
    w2c[i] = f2bf(w2[((ci * C2 + o) * 3 + fi) * 3 + fj]);
}

// x (NCHW fp32) -> xT[b][ih][iw][ci] bf16 via LDS transpose
__global__ __launch_bounds__(256) void xt_kernel(const float* __restrict__ x,
                                                 ushort_t* __restrict__ xT) {
    const int ih = blockIdx.x;
    const int b  = blockIdx.y;
    const int tid = threadIdx.x;
    __shared__ ushort_t tile[64 * 72];    // [iw][cc], stride 72 (16B-aligned rows)

    for (int chunk = 0; chunk < 4; ++chunk) {
        const int ci0 = chunk * 64;
        if (chunk) __syncthreads();
#pragma unroll
        for (int it = 0; it < 16; ++it) {
            const int cc = it * 4 + (tid >> 6);
            const int iw = tid & 63;
            const float v = x[(((size_t)b * C1 + ci0 + cc) * HH + ih) * WW + iw];
            tile[iw * 72 + cc] = f2bf(v);
        }
        __syncthreads();
#pragma unroll
        for (int it = 0; it < 2; ++it) {
            const int i  = it * 256 + tid;
            const int iw = i >> 3;
            const int t  = i & 7;
            const int4 v = *reinterpret_cast<const int4*>(&tile[iw * 72 + t * 8]);
            *reinterpret_cast<int4*>(&xT[(((size_t)(b * HH + ih) * WW) + iw) * C1 + ci0 + t * 8]) = v;
        }
    }
}

// ---------------------------------------------------------------------------
// k-kernel: kg[b][h][tap][w], 512 threads = 4 c-quarters x 128 w, LDS-reduced.
// ---------------------------------------------------------------------------
__global__ __launch_bounds__(512) void k_kernel(const float* __restrict__ guide,
                                                float* __restrict__ kg) {
    const int h = blockIdx.x;
    const int b = blockIdx.y;
    const int tid = threadIdx.x;
    const int cq  = tid >> 7;
    const int n   = tid & 127;

    float acc[9];
#pragma unroll
    for (int t = 0; t < 9; ++t) acc[t] = 0.f;

    const float* gb = guide + (size_t)b * C2 * H2 * W2;
    for (int c = cq * 32; c < cq * 32 + 32; ++c) {
        const float* grow = gb + (c * H2 + h) * W2;
        const float gc = grow[n];
#pragma unroll
        for (int di = 0; di < 3; ++di) {
            const int hh = h + di - 1;
            const bool rv = (hh >= 0) && (hh < H2);
            const float* gr = gb + (c * H2 + (rv ? hh : 0)) * W2;
#pragma unroll
            for (int dj = 0; dj < 3; ++dj) {
                const int col = n + dj - 1;
                const bool cv = rv && (col >= 0) && (col < W2);
                const float gn = cv ? gr[col] : 0.f;
                const float d = gn - gc;
                acc[di * 3 + dj] += d * d;
            }
        }
    }

    __shared__ float part[4][9][128];
#pragma unroll
    for (int t = 0; t < 9; ++t) part[cq][t][n] = acc[t];
    __syncthreads();

    for (int i = tid; i < 1152; i += 512) {
        const int t  = i >> 7;
        const int nn = i & 127;
        const float s = part[0][t][nn] + part[1][t][nn] + part[2][t][nn] + part[3][t][nn];
        kg[(size_t)(b * H2 + h) * 1152 + i] = __expf(-0.5f * s);
    }
}

// ---------------------------------------------------------------------------
// Deconv MFMA v4: tile 128co x 128pix, K=256 in 4 chunks of 64, 4 taps.
// v2 memory path (normal loads -> ds_write staging). Changes vs v2:
//  - B halo slab [3 ih][66 iw][64 ci] staged ONCE per kc (shared by 4 taps):
//    -75% B ds_write volume, barriers 64 -> 32.
//  - XOR-swizzled layouts (stride 128B rows, chunk ^= row&7): bank-balanced
//    ds_read_b128 on both A and B.
//  - T14 register prefetch: next A-tap / next kc's B-slab loaded into VGPRs
//    during the current GEMM; only ds_write remains after the barrier.
// Numerically identical (same kc,tap,k2 MFMA order).
// ---------------------------------------------------------------------------
__global__ __launch_bounds__(256, 2) void deconv_mfma(const ushort_t* __restrict__ xT,
                                                      const ushort_t* __restrict__ w1c,
                                                      const float* __restrict__ b1,
                                                      ushort_t* __restrict__ y) {
    const int pwc = blockIdx.x;
    const int pr  = blockIdx.y;
    const int b   = blockIdx.z;
    const int base_oh = (pr >> 1) * 4 + (pr & 1);
    const int p    = (base_oh + 1) & 1;
    const int ihA0 = (base_oh + 1 - p) >> 1;
    const int pwp  = 1 - pwc;
    const int cls  = p * 2 + pwp;

    const int tid  = threadIdx.x;
    const int lane = tid & 63;
    const int wave = tid >> 6;
    const int wm   = (wave & 1) * 64;
    const int wn   = (wave >> 1) * 64;
    const int quad = lane >> 4;
    const int l15  = lane & 15;

    // Bs: 198 pix x 64 ci = 12672 ushorts; As: 128 x 64 = 8192. Union w/
    // epilogue Ot (17408) -> 20864 ushorts = 41728 B -> up to 3 blocks/CU.
    __shared__ __align__(16) ushort_t lds[12672 + 8192];
    ushort_t* Bs = lds;
    ushort_t* As = lds + 12672;

    floatx4 acc[4][4];
#pragma unroll
    for (int mi = 0; mi < 4; ++mi)
#pragma unroll
        for (int ni = 0; ni < 4; ++ni) acc[mi][ni] = (floatx4)0.f;

    const int ihbase = ihA0 - 1;
    const int iwbase = pwc - 1;

    int4 bsreg[7];
    int4 asreg[4];

    // ---- prologue prefetch: B slab kc=0, A (kc=0, tap=0)
#pragma unroll
    for (int it = 0; it < 7; ++it) {
        const int i = it * 256 + tid;
        int4 v = make_int4(0, 0, 0, 0);
        if (i < 1584) {
            const int pix  = i >> 3;
            const int c    = i & 7;
            const int prow = pix / 66;
            const int pcol = pix - prow * 66;
            const int ih = ihbase + prow;
            const int iw = iwbase + pcol;
            if (ih >= 0 && ih < HH && iw >= 0 && iw < WW)
                v = *reinterpret_cast<const int4*>(
                    &xT[(((size_t)(b * HH + ih) * WW) + iw) * C1 + c * 8]);
        }
        bsreg[it] = v;
    }
#pragma unroll
    for (int it = 0; it < 4; ++it) {
        const int i   = it * 256 + tid;
        const int row = i >> 3;
        const int c   = i & 7;
        asreg[it] = *reinterpret_cast<const int4*>(
            &w1c[((size_t)(cls * 4 + 0) * 128 + row) * 256 + 0 * 64 + c * 8]);
    }

    for (int kc = 0; kc < 4; ++kc) {
        // ---- write staged B slab + A(tap0) (regs already loaded)
#pragma unroll
        for (int it = 0; it < 7; ++it) {
            const int i = it * 256 + tid;
            if (i < 1584) {
                const int pix = i >> 3;
                const int c   = i & 7;
                *reinterpret_cast<int4*>(&Bs[pix * 64 + ((c ^ (pix & 7)) << 3)]) = bsreg[it];
            }
        }
#pragma unroll
        for (int it = 0; it < 4; ++it) {
            const int i   = it * 256 + tid;
            const int row = i >> 3;
            const int c   = i & 7;
            *reinterpret_cast<int4*>(&As[row * 64 + ((c ^ (row & 7)) << 3)]) = asreg[it];
        }
        __syncthreads();

        for (int tap = 0; tap < 4; ++tap) {
            // ---- T14 prefetch next stage into regs (overlaps GEMM below)
            if (tap < 3) {
#pragma unroll
                for (int it = 0; it < 4; ++it) {
                    const int i   = it * 256 + tid;
                    const int row = i >> 3;
                    const int c   = i & 7;
                    asreg[it] = *reinterpret_cast<const int4*>(
                        &w1c[((size_t)(cls * 4 + tap + 1) * 128 + row) * 256 + kc * 64 + c * 8]);
                }
            } else if (kc < 3) {
#pragma unroll
                for (int it = 0; it < 7; ++it) {
                    const int i = it * 256 + tid;
                    int4 v = make_int4(0, 0, 0, 0);
                    if (i < 1584) {
                        const int pix  = i >> 3;
                        const int c    = i & 7;
                        const int prow = pix / 66;
                        const int pcol = pix - prow * 66;
                        const int ih = ihbase + prow;
                        const int iw = iwbase + pcol;
                        if (ih >= 0 && ih < HH && iw >= 0 && iw < WW)
                            v = *reinterpret_cast<const int4*>(
                                &xT[(((size_t)(b * HH + ih) * WW) + iw) * C1 + (kc + 1) * 64 + c * 8]);
                    }
                    bsreg[it] = v;
                }
#pragma unroll
                for (int it = 0; it < 4; ++it) {
                    const int i   = it * 256 + tid;
                    const int row = i >> 3;
                    const int c   = i & 7;
                    asreg[it] = *reinterpret_cast<const int4*>(
                        &w1c[((size_t)(cls * 4 + 0) * 128 + row) * 256 + (kc + 1) * 64 + c * 8]);
                }
            }

            const int th = tap >> 1, tw = tap & 1;
#pragma unroll
            for (int k2 = 0; k2 < 2; ++k2) {
                short8 af[4], bfr[4];
#pragma unroll
                for (int mi = 0; mi < 4; ++mi) {
                    const int row = wm + mi * 16 + l15;
                    af[mi] = *reinterpret_cast<const short8*>(
                        &As[row * 64 + (((k2 * 4 + quad) ^ (row & 7)) << 3)]);
                }
#pragma unroll
                for (int ni = 0; ni < 4; ++ni) {
                    const int n   = wn + ni * 16 + l15;
                    const int prw = (n >> 6) - th + 1;
                    const int pcl = (n & 63) + 1 - tw;
                    const int P   = prw * 66 + pcl;
                    bfr[ni] = *reinterpret_cast<const short8*>(
                        &Bs[P * 64 + (((k2 * 4 + quad) ^ (P & 7)) << 3)]);
                }
#pragma unroll
                for (int mi = 0; mi < 4; ++mi)
#pragma unroll
                    for (int ni = 0; ni < 4; ++ni)
                        acc[mi][ni] = __builtin_amdgcn_mfma_f32_16x16x32_bf16(
                            af[mi], bfr[ni], acc[mi][ni], 0, 0, 0);
            }
            __syncthreads();                       // readers of As/Bs done
            if (tap < 3) {
                // ---- write next A (loads already in flight / complete)
#pragma unroll
                for (int it = 0; it < 4; ++it) {
                    const int i   = it * 256 + tid;
                    const int row = i >> 3;
                    const int c   = i & 7;
                    *reinterpret_cast<int4*>(&As[row * 64 + ((c ^ (row & 7)) << 3)]) = asreg[it];
                }
                __syncthreads();
            }
            // tap==3: next kc writes Bs+As at loop top (barrier above covers WAR)
        }
    }

    // ---- epilogue: transpose in LDS -> y[b][oh][ow][co] bf16
    ushort_t* Ot = lds;                      // [n 0..127][co 0..127], stride 136
#pragma unroll
    for (int mi = 0; mi < 4; ++mi)
#pragma unroll
        for (int ni = 0; ni < 4; ++ni) {
            const int n = wn + ni * 16 + l15;
#pragma unroll
            for (int r = 0; r < 4; ++r) {
                const int co = wm + mi * 16 + quad * 4 + r;
                Ot[n * 136 + co] = f2bf(acc[mi][ni][r] + b1[co]);
            }
        }
    __syncthreads();
#pragma unroll
    for (int it = 0; it < 8; ++it) {
        const int i   = it * 256 + tid;
        const int n   = i >> 4;
        const int t   = i & 15;
        const int rh  = n >> 6;
        const int n64 = n & 63;
        const int oh  = base_oh + 2 * rh;
        const int ow  = 2 * n64 + pwc;
        const int4 v = *reinterpret_cast<const int4*>(&Ot[n * 136 + t * 8]);
        *reinterpret_cast<int4*>(&y[(((size_t)(b * H2 + oh) * W2) + ow) * C2 + t * 8]) = v;
    }
}

// ---------------------------------------------------------------------------
// PAC MFMA v4: tile 128o x 128w per (b,h). v2 memory path (normal loads ->
// ds_write staging, As+Ys in LDS, original grid). Changes vs v2:
//  - XOR-swizzled As/Ys (stride 256B rows, chunk ^= row&7): bank-balanced
//    ds_read_b128 (fixes the 8-way conflict of stride-272B).
//  - Ys merged into the A-phase at each di (12 phases -> 9).
//  - T14 register prefetch of the next A-tap during the current GEMM.
// Numerically identical to v2.
// ---------------------------------------------------------------------------
__global__ __launch_bounds__(256, 2) void pac_mfma(const ushort_t* __restrict__ y,
                                                   const float* __restrict__ kg,
                                                   const ushort_t* __restrict__ w2c,
                                                   const float* __restrict__ b2,
                                                   float* __restrict__ out) {
    const int h = blockIdx.x;
    const int b = blockIdx.y;

    const int tid  = threadIdx.x;
    const int lane = tid & 63;
    const int wave = tid >> 6;
    const int wm   = (wave & 1) * 64;
    const int wn   = (wave >> 1) * 64;
    const int quad = lane >> 4;
    const int l15  = lane & 15;

    __shared__ __align__(16) ushort_t As[128 * 128];   // weights per tap, swizzled
    __shared__ __align__(16) ushort_t Ys[130 * 128];   // y slab rows 0..129, swizzled
    __shared__ float k_lds[9 * 128];

    // zero halo rows 0 and 129 (2 rows x 16 chunks = 32 int4)
    if (tid < 32) {
        const int r = (tid >> 4) ? 129 : 0;
        *reinterpret_cast<int4*>(&Ys[r * 128 + (tid & 15) * 8]) = make_int4(0, 0, 0, 0);
    }
    for (int i = tid; i < 1152; i += 256)
        k_lds[i] = kg[(size_t)(b * H2 + h) * 1152 + i];

    const int dlo = (h == 0) ? 1 : 0;
    const int dhi = (h == H2 - 1) ? 1 : 2;

    float out_acc[4][4][4];
#pragma unroll
    for (int mi = 0; mi < 4; ++mi)
#pragma unroll
        for (int ni = 0; ni < 4; ++ni)
#pragma unroll
            for (int r = 0; r < 4; ++r) out_acc[mi][ni][r] = 0.f;

    // ---- prologue prefetch: A for first tap
    int4 areg[8];
    {
        const int tap0 = dlo * 3;
#pragma unroll
        for (int it = 0; it < 8; ++it) {
            const int i   = it * 256 + tid;
            const int row = i >> 4;
            const int c   = i & 15;
            areg[it] = *reinterpret_cast<const int4*>(
                &w2c[((size_t)(tap0 * 128 + row)) * 128 + c * 8]);
        }
    }

    for (int di = dlo; di <= dhi; ++di) {
        const int hh = h + di - 1;
        // ---- merged stage phase: Ys(di) rows 1..128 + As(tap di*3)
#pragma unroll
        for (int it = 0; it < 8; ++it) {
            const int i = it * 256 + tid;
            const int r = i >> 4;
            const int c = i & 15;
            const int4 v = *reinterpret_cast<const int4*>(
                &y[(((size_t)(b * H2 + hh) * W2) + r) * C2 + c * 8]);
            *reinterpret_cast<int4*>(&Ys[(r + 1) * 128 + ((c ^ ((r + 1) & 7)) << 3)]) = v;
        }
#pragma unroll
        for (int it = 0; it < 8; ++it) {
            const int i   = it * 256 + tid;
            const int row = i >> 4;
            const int c   = i & 15;
            *reinterpret_cast<int4*>(&As[row * 128 + ((c ^ (row & 7)) << 3)]) = areg[it];
        }
        __syncthreads();

        for (int dj = 0; dj < 3; ++dj) {
            const int tap = di * 3 + dj;
            // ---- T14 prefetch next A-tap (overlaps GEMM)
            const int ntap = (dj < 2) ? tap + 1 : ((di < dhi) ? (di + 1) * 3 : -1);
            if (ntap >= 0) {
#pragma unroll
                for (int it = 0; it < 8; ++it) {
                    const int i   = it * 256 + tid;
                    const int row = i >> 4;
                    const int c   = i & 15;
                    areg[it] = *reinterpret_cast<const int4*>(
                        &w2c[((size_t)(ntap * 128 + row)) * 128 + c * 8]);
                }
            }

            floatx4 acc[4][4];
#pragma unroll
            for (int mi = 0; mi < 4; ++mi)
#pragma unroll
                for (int ni = 0; ni < 4; ++ni) acc[mi][ni] = (floatx4)0.f;

#pragma unroll
            for (int kc = 0; kc < 4; ++kc) {
                short8 af[4], bfr[4];
#pragma unroll
                for (int mi = 0; mi < 4; ++mi) {
                    const int row = wm + mi * 16 + l15;
                    af[mi] = *reinterpret_cast<const short8*>(
                        &As[row * 128 + (((kc * 4 + quad) ^ (row & 7)) << 3)]);
                }
#pragma unroll
                for (int ni = 0; ni < 4; ++ni) {
                    const int R = wn + ni * 16 + l15 + dj;
                    bfr[ni] = *reinterpret_cast<const short8*>(
                        &Ys[R * 128 + (((kc * 4 + quad) ^ (R & 7)) << 3)]);
                }
#pragma unroll
                for (int mi = 0; mi < 4; ++mi)
#pragma unroll
                    for (int ni = 0; ni < 4; ++ni)
                        acc[mi][ni] = __builtin_amdgcn_mfma_f32_16x16x32_bf16(
                            af[mi], bfr[ni], acc[mi][ni], 0, 0, 0);
            }
            // ---- scale by k_tap[w] and accumulate
            float kv[4];
#pragma unroll
            for (int ni = 0; ni < 4; ++ni)
                kv[ni] = k_lds[tap * 128 + wn + ni * 16 + l15];
#pragma unroll
            for (int mi = 0; mi < 4; ++mi)
#pragma unroll
                for (int ni = 0; ni < 4; ++ni)
#pragma unroll
                    for (int r = 0; r < 4; ++r)
                        out_acc[mi][ni][r] += kv[ni] * acc[mi][ni][r];

            __syncthreads();                       // As/Ys readers done
            if (dj < 2) {
                // ---- write next A (loads already complete / in flight)
#pragma unroll
                for (int it = 0; it < 8; ++it) {
                    const int i   = it * 256 + tid;
                    const int row = i >> 4;
                    const int c   = i & 15;
                    *reinterpret_cast<int4*>(&As[row * 128 + ((c ^ (row & 7)) << 3)]) = areg[it];
                }
                __syncthreads();
            }
            // dj==2: next di writes Ys+As at loop top (barrier above covers WAR)
        }
    }

    // ---- final store: out NCHW fp32
#pragma unroll
    for (int mi = 0; mi < 4; ++mi)
#pragma unroll
        for (int ni = 0; ni < 4; ++ni) {
            const int w = wn + ni * 16 + l15;
#pragma unroll
            for (int r = 0; r < 4; ++r) {
                const int o = wm + mi * 16 + quad * 4 + r;
                out[(((size_t)b * C2 + o) * H2 + h) * W2 + w] = out_acc[mi][ni][r] + b2[o];
            }
        }
}

extern "C" void kernel_launch(void* const* d_in, const int* in_sizes, int n_in,
                              void* d_out, int out_size, void* d_ws, size_t ws_size,
                              hipStream_t stream) {
    const float* x     = (const float*)d_in[0];
    const float* guide = (const float*)d_in[1];
    const float* w1    = (const float*)d_in[2];
    const float* b1    = (const float*)d_in[3];
    const float* w2    = (const float*)d_in[4];
    const float* b2    = (const float*)d_in[5];
    float* out = (float*)d_out;

    ushort_t* w1c = (ushort_t*)((char*)d_ws + W1C_OFF);
    ushort_t* w2c = (ushort_t*)((char*)d_ws + W2C_OFF);
    float*    kg  = (float*)((char*)d_ws + KG_OFF);
    ushort_t* xT  = (ushort_t*)((char*)d_ws + XT_OFF);
    ushort_t* y   = (ushort_t*)((char*)d_ws + Y_OFF);

    w1c_kernel<<<W1C_ELEMS / 256, 256, 0, stream>>>(w1, w1c);
    w2c_kernel<<<W2C_ELEMS / 256, 256, 0, stream>>>(w2, w2c);
    xt_kernel<<<dim3(HH, B_), 256, 0, stream>>>(x, xT);
    k_kernel<<<dim3(H2, B_), 512, 0, stream>>>(guide, kg);
    deconv_mfma<<<dim3(2, 64, B_), 256, 0, stream>>>(xT, w1c, b1, y);
    pac_mfma<<<dim3(H2, B_), 256, 0, stream>>>(y, kg, w2c, b2, out);
}

// Round 3
// 199.755 us; speedup vs baseline: 1.4862x; 1.4862x over previous
//
#include <hip/hip_runtime.h>

#define B_  4
#define C1  256
#define C2  128
#define HH  64
#define WW  64
#define H2  128
#define W2  128

using short8  = __attribute__((ext_vector_type(8))) short;
using floatx4 = __attribute__((ext_vector_type(4))) float;
typedef unsigned short ushort_t;

#define GLOBAL_AS __attribute__((address_space(1)))
#define LDS_AS    __attribute__((address_space(3)))

// ---- workspace layout (bytes) ----
#define W1C_OFF 0u                                   // [cls4][tap4][co128][ci256] bf16
#define W1C_ELEMS (4 * 4 * 128 * 256)
#define W2C_OFF (W1C_ELEMS * 2u)                     // [tap9][o128][ci128] bf16 (granule-swizzled)
#define W2C_ELEMS (9 * 128 * 128)
#define KG_OFF  (W2C_OFF + W2C_ELEMS * 2u)           // [b][h][tap9][w128] fp32
#define KG_ELEMS (B_ * H2 * 9 * W2)
#define XT_OFF  (KG_OFF + KG_ELEMS * 4u)             // x -> [b][ih][iw][ci] bf16
#define XT_ELEMS (B_ * HH * WW * C1)
#define Y_OFF   (XT_OFF + XT_ELEMS * 2u)             // y -> [b][h][w][c] bf16
#define Y_ELEMS (B_ * H2 * W2 * C2)

static __device__ __forceinline__ ushort_t f2bf(float f) {
    union { float f; unsigned u; } v; v.f = f;
    unsigned r = v.u + 0x7FFFu + ((v.u >> 16) & 1u);   // RNE
    return (ushort_t)(r >> 16);
}

// ---------------------------------------------------------------------------
// Prep: w1 -> w1c[cls][tap][co][ci] bf16 (cls=p*2+pw', tap=th*2+tw)
// ---------------------------------------------------------------------------
__global__ void w1c_kernel(const float* __restrict__ w1, ushort_t* __restrict__ w1c) {
    int i = blockIdx.x * 256 + threadIdx.x;
    const int ci  = i & 255;
    const int co  = (i >> 8) & 127;
    const int tap = (i >> 15) & 3;
    const int cls = i >> 17;
    const int kh  = (cls >> 1) + 2 * (tap >> 1);
    const int kw  = (cls & 1) + 2 * (tap & 1);
    w1c[i] = f2bf(w1[((ci * C2 + co) * 4 + kh) * 4 + kw]);
}

// w2 -> w2c[tap][o][ci] bf16, flip baked in, 16B-granule XOR-swizzled by (o&7)
// so pac can global_load_lds it linearly and read with the XOR.
__global__ void w2c_kernel(const float* __restrict__ w2, ushort_t* __restrict__ w2c) {
    int i = blockIdx.x * 256 + threadIdx.x;
    const int ci  = i & 127;
    const int o   = (i >> 7) & 127;
    const int tap = i >> 14;
    const int fi  = 2 - tap / 3;
    const int fj  = 2 - tap % 3;
    const int gs  = ((((ci >> 3) ^ (o & 7)) << 3) | (ci & 7));
    w2c[tap * 16384 + o * 128 + gs] = f2bf(w2[((ci * C2 + o) * 3 + fi) * 3 + fj]);
}

// x (NCHW fp32) -> xT[b][ih][iw][ci] bf16 via LDS transpose
__global__ __launch_bounds__(256) void xt_kernel(const float* __restrict__ x,
                                                 ushort_t* __restrict__ xT) {
    const int ih = blockIdx.x;
    const int b  = blockIdx.y;
    const int tid = threadIdx.x;
    __shared__ ushort_t tile[64 * 72];    // [iw][cc], stride 72 (16B-aligned rows)

    for (int chunk = 0; chunk < 4; ++chunk) {
        const int ci0 = chunk * 64;
        if (chunk) __syncthreads();
#pragma unroll
        for (int it = 0; it < 16; ++it) {
            const int cc = it * 4 + (tid >> 6);
            const int iw = tid & 63;
            const float v = x[(((size_t)b * C1 + ci0 + cc) * HH + ih) * WW + iw];
            tile[iw * 72 + cc] = f2bf(v);
        }
        __syncthreads();
#pragma unroll
        for (int it = 0; it < 2; ++it) {
            const int i  = it * 256 + tid;
            const int iw = i >> 3;
            const int t  = i & 7;
            const int4 v = *reinterpret_cast<const int4*>(&tile[iw * 72 + t * 8]);
            *reinterpret_cast<int4*>(&xT[(((size_t)(b * HH + ih) * WW) + iw) * C1 + ci0 + t * 8]) = v;
        }
    }
}

// ---------------------------------------------------------------------------
// k-kernel: kg[b][h][tap][w], 512 threads = 4 c-quarters x 128 w, LDS-reduced.
// ---------------------------------------------------------------------------
__global__ __launch_bounds__(512) void k_kernel(const float* __restrict__ guide,
                                                float* __restrict__ kg) {
    const int h = blockIdx.x;
    const int b = blockIdx.y;
    const int tid = threadIdx.x;
    const int cq  = tid >> 7;
    const int n   = tid & 127;

    float acc[9];
#pragma unroll
    for (int t = 0; t < 9; ++t) acc[t] = 0.f;

    const float* gb = guide + (size_t)b * C2 * H2 * W2;
    for (int c = cq * 32; c < cq * 32 + 32; ++c) {
        const float* grow = gb + (c * H2 + h) * W2;
        const float gc = grow[n];
#pragma unroll
        for (int di = 0; di < 3; ++di) {
            const int hh = h + di - 1;
            const bool rv = (hh >= 0) && (hh < H2);
            const float* gr = gb + (c * H2 + (rv ? hh : 0)) * W2;
#pragma unroll
            for (int dj = 0; dj < 3; ++dj) {
                const int col = n + dj - 1;
                const bool cv = rv && (col >= 0) && (col < W2);
                const float gn = cv ? gr[col] : 0.f;
                const float d = gn - gc;
                acc[di * 3 + dj] += d * d;
            }
        }
    }

    __shared__ float part[4][9][128];
#pragma unroll
    for (int t = 0; t < 9; ++t) part[cq][t][n] = acc[t];
    __syncthreads();

    for (int i = tid; i < 1152; i += 512) {
        const int t  = i >> 7;
        const int nn = i & 127;
        const float s = part[0][t][nn] + part[1][t][nn] + part[2][t][nn] + part[3][t][nn];
        kg[(size_t)(b * H2 + h) * 1152 + i] = __expf(-0.5f * s);
    }
}

// ---------------------------------------------------------------------------
// Deconv MFMA (exact v2, known-good): tile 128co x 128pix, K=256 in 4 chunks
// of 64, 4 taps. A = w1c rows, B = xT rows staged per (kc,tap).
// ---------------------------------------------------------------------------
__global__ __launch_bounds__(256, 2) void deconv_mfma(const ushort_t* __restrict__ xT,
                                                      const ushort_t* __restrict__ w1c,
                                                      const float* __restrict__ b1,
                                                      ushort_t* __restrict__ y) {
    const int pwc = blockIdx.x;
    const int pr  = blockIdx.y;
    const int b   = blockIdx.z;
    const int base_oh = (pr >> 1) * 4 + (pr & 1);
    const int p    = (base_oh + 1) & 1;
    const int ihA0 = (base_oh + 1 - p) >> 1;
    const int pwp  = 1 - pwc;
    const int cls  = p * 2 + pwp;

    const int tid  = threadIdx.x;
    const int lane = tid & 63;
    const int wave = tid >> 6;
    const int wm   = (wave & 1) * 64;
    const int wn   = (wave >> 1) * 64;
    const int quad = lane >> 4;
    const int l15  = lane & 15;

    __shared__ __align__(16) ushort_t lds[2 * 128 * 72];   // As | Bs, stride 72
    ushort_t* As = lds;
    ushort_t* Bs = lds + 128 * 72;

    floatx4 acc[4][4];
#pragma unroll
    for (int mi = 0; mi < 4; ++mi)
#pragma unroll
        for (int ni = 0; ni < 4; ++ni) acc[mi][ni] = (floatx4)0.f;

    for (int kc = 0; kc < 4; ++kc) {
        const int ci0 = kc * 64;
        for (int tap = 0; tap < 4; ++tap) {
            const int th = tap >> 1, tw = tap & 1;
            __syncthreads();
            // ---- stage A: 128 rows x 64 ci = 1024 int4
#pragma unroll
            for (int it = 0; it < 4; ++it) {
                const int i   = it * 256 + tid;
                const int row = i >> 3;
                const int t   = i & 7;
                const int4 v = *reinterpret_cast<const int4*>(
                    &w1c[((size_t)(cls * 4 + tap) * 128 + row) * 256 + ci0 + t * 8]);
                *reinterpret_cast<int4*>(&As[row * 72 + t * 8]) = v;
            }
            // ---- stage B: 128 rows x 64 ci from xT (zero OOB rows)
#pragma unroll
            for (int it = 0; it < 4; ++it) {
                const int i   = it * 256 + tid;
                const int row = i >> 3;
                const int t   = i & 7;
                const int rh  = row >> 6;
                const int n64 = row & 63;
                const int ih  = ihA0 + rh - th;
                const int iw  = n64 + pwc - tw;
                int4 v = make_int4(0, 0, 0, 0);
                if (ih >= 0 && ih < HH && iw >= 0 && iw < WW)
                    v = *reinterpret_cast<const int4*>(
                        &xT[(((size_t)(b * HH + ih) * WW) + iw) * C1 + ci0 + t * 8]);
                *reinterpret_cast<int4*>(&Bs[row * 72 + t * 8]) = v;
            }
            __syncthreads();
#pragma unroll
            for (int k2 = 0; k2 < 2; ++k2) {
                short8 af[4], bfr[4];
#pragma unroll
                for (int mi = 0; mi < 4; ++mi)
                    af[mi] = *reinterpret_cast<const short8*>(
                        &As[(wm + mi * 16 + l15) * 72 + k2 * 32 + quad * 8]);
#pragma unroll
                for (int ni = 0; ni < 4; ++ni)
                    bfr[ni] = *reinterpret_cast<const short8*>(
                        &Bs[(wn + ni * 16 + l15) * 72 + k2 * 32 + quad * 8]);
#pragma unroll
                for (int mi = 0; mi < 4; ++mi)
#pragma unroll
                    for (int ni = 0; ni < 4; ++ni)
                        acc[mi][ni] = __builtin_amdgcn_mfma_f32_16x16x32_bf16(
                            af[mi], bfr[ni], acc[mi][ni], 0, 0, 0);
            }
        }
    }

    // ---- epilogue: transpose in LDS -> y[b][oh][ow][co] bf16
    __syncthreads();
    ushort_t* Ot = lds;                      // [n 0..127][co 0..127], stride 136
#pragma unroll
    for (int mi = 0; mi < 4; ++mi)
#pragma unroll
        for (int ni = 0; ni < 4; ++ni) {
            const int n = wn + ni * 16 + l15;
#pragma unroll
            for (int r = 0; r < 4; ++r) {
                const int co = wm + mi * 16 + quad * 4 + r;
                Ot[n * 136 + co] = f2bf(acc[mi][ni][r] + b1[co]);
            }
        }
    __syncthreads();
#pragma unroll
    for (int it = 0; it < 8; ++it) {
        const int i   = it * 256 + tid;
        const int n   = i >> 4;
        const int t   = i & 15;
        const int rh  = n >> 6;
        const int n64 = n & 63;
        const int oh  = base_oh + 2 * rh;
        const int ow  = 2 * n64 + pwc;
        const int4 v = *reinterpret_cast<const int4*>(&Ot[n * 136 + t * 8]);
        *reinterpret_cast<int4*>(&y[(((size_t)(b * H2 + oh) * W2) + ow) * C2 + t * 8]) = v;
    }
}

// ---------------------------------------------------------------------------
// PAC MFMA v5: one 512-thread block per (b, 2 output rows). Grid = 256 blocks
// = exactly 1/CU. LDS = 4 y-slabs (4 x 32KB) + As (32KB) = 160 KiB exactly.
//  - 8 waves: wave = rsub*4 + quadrant; per-wave registers identical to v2
//    (out_acc 64 + acc 64) -> no spill (v3/v4 lesson: budget is 256/wave).
//  - y slabs staged ONCE in prologue (ordinary loads, XOR-swizzled ds_write).
//  - As staged per tap via global_load_lds (ZERO registers; w2c pre-swizzled
//    so LDS dest and global src are both linear; GEMM reads apply the XOR).
//  - Stage phases per CU: 24 -> 13; barriers per CU: 42 -> 17.
//  - Edge taps handled by zero-predicated B fragments (adds exact 0.0 to
//    out_acc -> bit-identical to v2's tap skipping).
// ---------------------------------------------------------------------------
__global__ __launch_bounds__(512, 2) void pac_mfma(const ushort_t* __restrict__ y,
                                                   const float* __restrict__ kg,
                                                   const ushort_t* __restrict__ w2c,
                                                   const float* __restrict__ b2,
                                                   float* __restrict__ out) {
    const int hblk = blockIdx.x;
    const int b    = blockIdx.y;
    const int h0   = hblk * 2;

    const int tid  = threadIdx.x;
    const int lane = tid & 63;
    const int wave = tid >> 6;          // 0..7
    const int rsub = wave >> 2;         // which of the 2 output rows
    const int q    = wave & 3;          // quadrant
    const int wm   = (q & 1) * 64;
    const int wn   = (q >> 1) * 64;
    const int quad = lane >> 4;
    const int l15  = lane & 15;
    const int h    = h0 + rsub;

    __shared__ __align__(16) ushort_t SLAB[4][128 * 128];  // [s][w][granule^swz]
    __shared__ __align__(16) ushort_t AS[128 * 128];       // [o][granule^swz]

    // ---- prologue: stage 4 y slabs (slab s <-> y row h0-1+s)
#pragma unroll 1
    for (int s = 0; s < 4; ++s) {
        const int hh = h0 - 1 + s;
        if (hh < 0 || hh >= H2) continue;              // block-uniform
        const ushort_t* ysrc = y + (size_t)(b * H2 + hh) * W2 * C2;
#pragma unroll
        for (int it = 0; it < 4; ++it) {
            const int i = it * 512 + tid;              // granule 0..2047
            const int w = i >> 4;
            const int c = i & 15;
            const int4 v = *reinterpret_cast<const int4*>(&ysrc[i * 8]);
            *reinterpret_cast<int4*>(&SLAB[s][w * 128 + ((c ^ (w & 7)) << 3)]) = v;
        }
    }
    // ---- issue As(tap 0): linear global_load_lds (w2c is pre-swizzled)
#pragma unroll
    for (int it = 0; it < 4; ++it) {
        const int i = it * 512 + tid;
        __builtin_amdgcn_global_load_lds((const GLOBAL_AS void*)(w2c + i * 8),
                                         (LDS_AS void*)(&AS[i * 8]), 16, 0, 0);
    }
    __syncthreads();

    float out_acc[4][4][4];
#pragma unroll
    for (int mi = 0; mi < 4; ++mi)
#pragma unroll
        for (int ni = 0; ni < 4; ++ni)
#pragma unroll
            for (int r = 0; r < 4; ++r) out_acc[mi][ni][r] = 0.f;

#pragma unroll 1
    for (int di = 0; di < 3; ++di) {
        const int hh  = h + di - 1;                     // per-wave row validity
        const bool hok = (hh >= 0) && (hh < H2);
        const ushort_t* SB = &SLAB[rsub + di][0];
#pragma unroll 1
        for (int dj = 0; dj < 3; ++dj) {
            const int tap = di * 3 + dj;

            float kv[4];
#pragma unroll
            for (int ni = 0; ni < 4; ++ni)
                kv[ni] = kg[(size_t)(b * H2 + h) * 1152 + tap * 128 + wn + ni * 16 + l15];

            floatx4 acc[4][4];
#pragma unroll
            for (int mi = 0; mi < 4; ++mi)
#pragma unroll
                for (int ni = 0; ni < 4; ++ni) acc[mi][ni] = (floatx4)0.f;

#pragma unroll
            for (int kc = 0; kc < 4; ++kc) {
                short8 af[4], bfr[4];
#pragma unroll
                for (int mi = 0; mi < 4; ++mi) {
                    const int row = wm + mi * 16 + l15;
                    af[mi] = *reinterpret_cast<const short8*>(
                        &AS[row * 128 + (((kc * 4 + quad) ^ (row & 7)) << 3)]);
                }
#pragma unroll
                for (int ni = 0; ni < 4; ++ni) {
                    const int col  = wn + ni * 16 + l15 + dj - 1;
                    const int colc = col & 127;
                    const short8 t = *reinterpret_cast<const short8*>(
                        &SB[colc * 128 + (((kc * 4 + quad) ^ (colc & 7)) << 3)]);
                    const bool ok = hok && (col >= 0) && (col < W2);
                    bfr[ni] = ok ? t : (short8)0;
                }
#pragma unroll
                for (int mi = 0; mi < 4; ++mi)
#pragma unroll
                    for (int ni = 0; ni < 4; ++ni)
                        acc[mi][ni] = __builtin_amdgcn_mfma_f32_16x16x32_bf16(
                            af[mi], bfr[ni], acc[mi][ni], 0, 0, 0);
            }
            // ---- scale by k_tap[w] and accumulate (adds exact 0 for edge taps)
#pragma unroll
            for (int mi = 0; mi < 4; ++mi)
#pragma unroll
                for (int ni = 0; ni < 4; ++ni)
#pragma unroll
                    for (int r = 0; r < 4; ++r)
                        out_acc[mi][ni][r] += kv[ni] * acc[mi][ni][r];

            if (tap < 8) {
                __syncthreads();                        // all AS readers done
                const ushort_t* wsrc = w2c + (size_t)(tap + 1) * 16384;
#pragma unroll
                for (int it = 0; it < 4; ++it) {
                    const int i = it * 512 + tid;
                    __builtin_amdgcn_global_load_lds((const GLOBAL_AS void*)(wsrc + i * 8),
                                                     (LDS_AS void*)(&AS[i * 8]), 16, 0, 0);
                }
                __syncthreads();                        // AS(tap+1) resident
            }
        }
    }

    // ---- final store: out NCHW fp32
#pragma unroll
    for (int mi = 0; mi < 4; ++mi)
#pragma unroll
        for (int ni = 0; ni < 4; ++ni) {
            const int w = wn + ni * 16 + l15;
#pragma unroll
            for (int r = 0; r < 4; ++r) {
                const int o = wm + mi * 16 + quad * 4 + r;
                out[(((size_t)b * C2 + o) * H2 + h) * W2 + w] = out_acc[mi][ni][r] + b2[o];
            }
        }
}

extern "C" void kernel_launch(void* const* d_in, const int* in_sizes, int n_in,
                              void* d_out, int out_size, void* d_ws, size_t ws_size,
                              hipStream_t stream) {
    const float* x     = (const float*)d_in[0];
    const float* guide = (const float*)d_in[1];
    const float* w1    = (const float*)d_in[2];
    const float* b1    = (const float*)d_in[3];
    const float* w2    = (const float*)d_in[4];
    const float* b2    = (const float*)d_in[5];
    float* out = (float*)d_out;

    ushort_t* w1c = (ushort_t*)((char*)d_ws + W1C_OFF);
    ushort_t* w2c = (ushort_t*)((char*)d_ws + W2C_OFF);
    float*    kg  = (float*)((char*)d_ws + KG_OFF);
    ushort_t* xT  = (ushort_t*)((char*)d_ws + XT_OFF);
    ushort_t* y   = (ushort_t*)((char*)d_ws + Y_OFF);

    w1c_kernel<<<W1C_ELEMS / 256, 256, 0, stream>>>(w1, w1c);
    w2c_kernel<<<W2C_ELEMS / 256, 256, 0, stream>>>(w2, w2c);
    xt_kernel<<<dim3(HH, B_), 256, 0, stream>>>(x, xT);
    k_kernel<<<dim3(H2, B_), 512, 0, stream>>>(guide, kg);
    deconv_mfma<<<dim3(2, 64, B_), 256, 0, stream>>>(xT, w1c, b1, y);
    pac_mfma<<<dim3(64, B_), 512, 0, stream>>>(y, kg, w2c, b2, out);
}

// Round 4
// 184.273 us; speedup vs baseline: 1.6111x; 1.0840x over previous
//
#include <hip/hip_runtime.h>

#define B_  4
#define C1  256
#define C2  128
#define HH  64
#define WW  64
#define H2  128
#define W2  128

using short8  = __attribute__((ext_vector_type(8))) short;
using floatx4 = __attribute__((ext_vector_type(4))) float;
typedef unsigned short ushort_t;

#define GLOBAL_AS __attribute__((address_space(1)))
#define LDS_AS    __attribute__((address_space(3)))

// ---- workspace layout (bytes) ----
#define W1C_OFF 0u                                   // [kc4][tap4][p2][pwp2][co128][ci64] bf16, granule-swizzled
#define W1C_ELEMS (4 * 4 * 128 * 256)
#define W2C_OFF (W1C_ELEMS * 2u)                     // [tap9][o128][ci128] bf16 (granule-swizzled)
#define W2C_ELEMS (9 * 128 * 128)
#define KG_OFF  (W2C_OFF + W2C_ELEMS * 2u)           // [b][h][tap9][w128] fp32
#define KG_ELEMS (B_ * H2 * 9 * W2)
#define XT_OFF  (KG_OFF + KG_ELEMS * 4u)             // x -> [b][ih][iw][ci] bf16
#define XT_ELEMS (B_ * HH * WW * C1)
#define Y_OFF   (XT_OFF + XT_ELEMS * 2u)             // y -> [b][h][w][c] bf16
#define Y_ELEMS (B_ * H2 * W2 * C2)

static __device__ __forceinline__ ushort_t f2bf(float f) {
    union { float f; unsigned u; } v; v.f = f;
    unsigned r = v.u + 0x7FFFu + ((v.u >> 16) & 1u);   // RNE
    return (ushort_t)(r >> 16);
}

// ---------------------------------------------------------------------------
// Prep: w1 -> w1s[kc][tap][p][pwp][co][ci64] bf16, 16B-granule XOR-swizzled
// by (co&7) so deconv can global_load_lds it linearly and read with the XOR.
// ---------------------------------------------------------------------------
__global__ void w1c_kernel(const float* __restrict__ w1, ushort_t* __restrict__ w1c) {
    int i = blockIdx.x * 256 + threadIdx.x;
    const int sub = i & 7;
    const int gs  = (i >> 3) & 7;
    const int co  = (i >> 6) & 127;
    const int pwp = (i >> 13) & 1;
    const int p   = (i >> 14) & 1;
    const int tap = (i >> 15) & 3;
    const int kc  = (i >> 17) & 3;
    const int ci  = kc * 64 + (((gs ^ (co & 7)) << 3) | sub);
    const int kh  = p + 2 * (tap >> 1);
    const int kw  = pwp + 2 * (tap & 1);
    w1c[i] = f2bf(w1[((ci * C2 + co) * 4 + kh) * 4 + kw]);
}

// w2 -> w2c[tap][o][ci] bf16, flip baked in, 16B-granule XOR-swizzled by (o&7)
// so pac can global_load_lds it linearly and read with the XOR.
__global__ void w2c_kernel(const float* __restrict__ w2, ushort_t* __restrict__ w2c) {
    int i = blockIdx.x * 256 + threadIdx.x;
    const int ci  = i & 127;
    const int o   = (i >> 7) & 127;
    const int tap = i >> 14;
    const int fi  = 2 - tap / 3;
    const int fj  = 2 - tap % 3;
    const int gs  = ((((ci >> 3) ^ (o & 7)) << 3) | (ci & 7));
    w2c[tap * 16384 + o * 128 + gs] = f2bf(w2[((ci * C2 + o) * 3 + fi) * 3 + fj]);
}

// x (NCHW fp32) -> xT[b][ih][iw][ci] bf16 via LDS transpose
__global__ __launch_bounds__(256) void xt_kernel(const float* __restrict__ x,
                                                 ushort_t* __restrict__ xT) {
    const int ih = blockIdx.x;
    const int b  = blockIdx.y;
    const int tid = threadIdx.x;
    __shared__ ushort_t tile[64 * 72];    // [iw][cc], stride 72 (16B-aligned rows)

    for (int chunk = 0; chunk < 4; ++chunk) {
        const int ci0 = chunk * 64;
        if (chunk) __syncthreads();
#pragma unroll
        for (int it = 0; it < 16; ++it) {
            const int cc = it * 4 + (tid >> 6);
            const int iw = tid & 63;
            const float v = x[(((size_t)b * C1 + ci0 + cc) * HH + ih) * WW + iw];
            tile[iw * 72 + cc] = f2bf(v);
        }
        __syncthreads();
#pragma unroll
        for (int it = 0; it < 2; ++it) {
            const int i  = it * 256 + tid;
            const int iw = i >> 3;
            const int t  = i & 7;
            const int4 v = *reinterpret_cast<const int4*>(&tile[iw * 72 + t * 8]);
            *reinterpret_cast<int4*>(&xT[(((size_t)(b * HH + ih) * WW) + iw) * C1 + ci0 + t * 8]) = v;
        }
    }
}

// ---------------------------------------------------------------------------
// k-kernel: kg[b][h][tap][w], 512 threads = 4 c-quarters x 128 w, LDS-reduced.
// ---------------------------------------------------------------------------
__global__ __launch_bounds__(512) void k_kernel(const float* __restrict__ guide,
                                                float* __restrict__ kg) {
    const int h = blockIdx.x;
    const int b = blockIdx.y;
    const int tid = threadIdx.x;
    const int cq  = tid >> 7;
    const int n   = tid & 127;

    float acc[9];
#pragma unroll
    for (int t = 0; t < 9; ++t) acc[t] = 0.f;

    const float* gb = guide + (size_t)b * C2 * H2 * W2;
    for (int c = cq * 32; c < cq * 32 + 32; ++c) {
        const float* grow = gb + (c * H2 + h) * W2;
        const float gc = grow[n];
#pragma unroll
        for (int di = 0; di < 3; ++di) {
            const int hh = h + di - 1;
            const bool rv = (hh >= 0) && (hh < H2);
            const float* gr = gb + (c * H2 + (rv ? hh : 0)) * W2;
#pragma unroll
            for (int dj = 0; dj < 3; ++dj) {
                const int col = n + dj - 1;
                const bool cv = rv && (col >= 0) && (col < W2);
                const float gn = cv ? gr[col] : 0.f;
                const float d = gn - gc;
                acc[di * 3 + dj] += d * d;
            }
        }
    }

    __shared__ float part[4][9][128];
#pragma unroll
    for (int t = 0; t < 9; ++t) part[cq][t][n] = acc[t];
    __syncthreads();

    for (int i = tid; i < 1152; i += 512) {
        const int t  = i >> 7;
        const int nn = i & 127;
        const float s = part[0][t][nn] + part[1][t][nn] + part[2][t][nn] + part[3][t][nn];
        kg[(size_t)(b * H2 + h) * 1152 + i] = __expf(-0.5f * s);
    }
}

// ---------------------------------------------------------------------------
// Deconv MFMA v6: one 512-thread block per (b, pr) covering BOTH pwc halves.
// Output 128co x 256pix (2 oh rows x 128 ow). Grid 64x4 = 256 = 1 block/CU.
//  - B halo slab [3 ih][64 iw][256 ci] = 96 KB staged ONCE in prologue
//    (XOR-swizzled granules; OOB-ih rows zeroed at stage, OOB-iw columns
//    zero-predicated at fragment read -> bit-identical to v2's zeroing).
//  - A streamed per (kc,tap) phase via global_load_lds, double-buffered
//    (2 x 32 KB, w1s pre-swizzled, linear dest): zero staging registers,
//    loads fly under the previous phase's GEMM. ONE barrier per phase.
//  - LDS = 96 + 64 = 160 KiB exactly. Epilogue Ot reuses the B region.
// Same (kc,tap,k2) accumulation order as v2 -> bit-identical y.
// ---------------------------------------------------------------------------
__global__ __launch_bounds__(512, 2) void deconv_mfma(const ushort_t* __restrict__ xT,
                                                      const ushort_t* __restrict__ w1s,
                                                      const float* __restrict__ b1,
                                                      ushort_t* __restrict__ y) {
    const int pr = blockIdx.x;
    const int b  = blockIdx.y;
    const int base_oh = (pr >> 1) * 4 + (pr & 1);
    const int p    = (base_oh + 1) & 1;
    const int ihA0 = (base_oh + 1 - p) >> 1;

    const int tid  = threadIdx.x;
    const int lane = tid & 63;
    const int wave = tid >> 6;          // 0..7
    const int pwc  = wave >> 2;         // output-column parity half
    const int q    = wave & 3;          // quadrant
    const int wm   = (q & 1) * 64;
    const int wn   = (q >> 1) * 64;
    const int quad = lane >> 4;
    const int l15  = lane & 15;
    const int pwp  = 1 - pwc;

    __shared__ __align__(16) ushort_t BS[3 * 64 * 256];      // 98304 B
    __shared__ __align__(16) ushort_t AS[2][2 * 128 * 64];   // 2 x 32768 B

    // ---- prologue: issue A(phase 0) via global_load_lds (zero registers)
    {
        const ushort_t* src = w1s + (size_t)(0 * 2 + p) * 16384;
#pragma unroll
        for (int it = 0; it < 4; ++it) {
            const int i = it * 512 + tid;
            __builtin_amdgcn_global_load_lds((const GLOBAL_AS void*)(src + i * 8),
                                             (LDS_AS void*)(&AS[0][i * 8]), 16, 0, 0);
        }
    }
    // ---- stage B slab: rows ihA0-1..ihA0+1, 6144 granules, zero OOB rows
#pragma unroll
    for (int it = 0; it < 12; ++it) {
        const int i   = it * 512 + tid;      // 0..6143
        const int pix = i >> 5;              // 0..191
        const int g   = i & 31;
        const int sr  = pix >> 6;
        const int iw  = pix & 63;
        const int ih  = ihA0 - 1 + sr;
        int4 v = make_int4(0, 0, 0, 0);
        if (ih >= 0 && ih < HH)
            v = *reinterpret_cast<const int4*>(
                &xT[(((size_t)(b * HH + ih) * WW) + iw) * C1 + g * 8]);
        *reinterpret_cast<int4*>(&BS[pix * 256 + ((g ^ (pix & 7)) << 3)]) = v;
    }
    __syncthreads();

    floatx4 acc[4][4];
#pragma unroll
    for (int mi = 0; mi < 4; ++mi)
#pragma unroll
        for (int ni = 0; ni < 4; ++ni) acc[mi][ni] = (floatx4)0.f;

#pragma unroll 1
    for (int ph = 0; ph < 16; ++ph) {        // ph = kc*4 + tap (v2 order)
        const int kc  = ph >> 2;
        const int tap = ph & 3;
        const int cur = ph & 1;
        // ---- issue next A into the other buffer (flies under this GEMM)
        if (ph < 15) {
            const ushort_t* src = w1s + (size_t)((ph + 1) * 2 + p) * 16384;
#pragma unroll
            for (int it = 0; it < 4; ++it) {
                const int i = it * 512 + tid;
                __builtin_amdgcn_global_load_lds((const GLOBAL_AS void*)(src + i * 8),
                                                 (LDS_AS void*)(&AS[cur ^ 1][i * 8]), 16, 0, 0);
            }
        }
        const int th = tap >> 1, tw = tap & 1;
#pragma unroll
        for (int k2 = 0; k2 < 2; ++k2) {
            short8 af[4], bfr[4];
#pragma unroll
            for (int mi = 0; mi < 4; ++mi) {
                const int row = wm + mi * 16 + l15;
                af[mi] = *reinterpret_cast<const short8*>(
                    &AS[cur][pwp * 8192 + row * 64 + (((k2 * 4 + quad) ^ (row & 7)) << 3)]);
            }
#pragma unroll
            for (int ni = 0; ni < 4; ++ni) {
                const int n   = wn + ni * 16 + l15;
                const int rh  = n >> 6;
                const int n64 = n & 63;
                const int iw  = n64 + pwc - tw;
                const int pix = (rh - th + 1) * 64 + (iw & 63);
                const short8 t = *reinterpret_cast<const short8*>(
                    &BS[pix * 256 + kc * 64 + (((k2 * 4 + quad) ^ (pix & 7)) << 3)]);
                const bool ok = (iw >= 0) && (iw < WW);
                bfr[ni] = ok ? t : (short8)0;
            }
#pragma unroll
            for (int mi = 0; mi < 4; ++mi)
#pragma unroll
                for (int ni = 0; ni < 4; ++ni)
                    acc[mi][ni] = __builtin_amdgcn_mfma_f32_16x16x32_bf16(
                        af[mi], bfr[ni], acc[mi][ni], 0, 0, 0);
        }
        __syncthreads();   // AS[cur] readers done; AS[cur^1] resident (vmcnt drain)
    }

    // ---- epilogue: transpose in LDS (reuse BS) -> y[b][oh][ow][co] bf16
    ushort_t* Ot = BS;                       // [256 pix][128 co], stride 136
#pragma unroll
    for (int mi = 0; mi < 4; ++mi)
#pragma unroll
        for (int ni = 0; ni < 4; ++ni) {
            const int n = wn + ni * 16 + l15;
#pragma unroll
            for (int r = 0; r < 4; ++r) {
                const int co = wm + mi * 16 + quad * 4 + r;
                Ot[(pwc * 128 + n) * 136 + co] = f2bf(acc[mi][ni][r] + b1[co]);
            }
        }
    __syncthreads();
#pragma unroll
    for (int it = 0; it < 8; ++it) {
        const int i    = it * 512 + tid;
        const int n_   = i >> 4;             // 0..255
        const int t    = i & 15;
        const int half = n_ >> 7;
        const int n    = n_ & 127;
        const int rh   = n >> 6;
        const int n64  = n & 63;
        const int oh   = base_oh + 2 * rh;
        const int ow   = 2 * n64 + half;
        const int4 v = *reinterpret_cast<const int4*>(&Ot[n_ * 136 + t * 8]);
        *reinterpret_cast<int4*>(&y[(((size_t)(b * H2 + oh) * W2) + ow) * C2 + t * 8]) = v;
    }
}

// ---------------------------------------------------------------------------
// PAC MFMA v5 (unchanged, known-good): one 512-thread block per (b, 2 rows).
// ---------------------------------------------------------------------------
__global__ __launch_bounds__(512, 2) void pac_mfma(const ushort_t* __restrict__ y,
                                                   const float* __restrict__ kg,
                                                   const ushort_t* __restrict__ w2c,
                                                   const float* __restrict__ b2,
                                                   float* __restrict__ out) {
    const int hblk = blockIdx.x;
    const int b    = blockIdx.y;
    const int h0   = hblk * 2;

    const int tid  = threadIdx.x;
    const int lane = tid & 63;
    const int wave = tid >> 6;          // 0..7
    const int rsub = wave >> 2;         // which of the 2 output rows
    const int q    = wave & 3;          // quadrant
    const int wm   = (q & 1) * 64;
    const int wn   = (q >> 1) * 64;
    const int quad = lane >> 4;
    const int l15  = lane & 15;
    const int h    = h0 + rsub;

    __shared__ __align__(16) ushort_t SLAB[4][128 * 128];  // [s][w][granule^swz]
    __shared__ __align__(16) ushort_t AS[128 * 128];       // [o][granule^swz]

    // ---- prologue: stage 4 y slabs (slab s <-> y row h0-1+s)
#pragma unroll 1
    for (int s = 0; s < 4; ++s) {
        const int hh = h0 - 1 + s;
        if (hh < 0 || hh >= H2) continue;              // block-uniform
        const ushort_t* ysrc = y + (size_t)(b * H2 + hh) * W2 * C2;
#pragma unroll
        for (int it = 0; it < 4; ++it) {
            const int i = it * 512 + tid;              // granule 0..2047
            const int w = i >> 4;
            const int c = i & 15;
            const int4 v = *reinterpret_cast<const int4*>(&ysrc[i * 8]);
            *reinterpret_cast<int4*>(&SLAB[s][w * 128 + ((c ^ (w & 7)) << 3)]) = v;
        }
    }
    // ---- issue As(tap 0): linear global_load_lds (w2c is pre-swizzled)
#pragma unroll
    for (int it = 0; it < 4; ++it) {
        const int i = it * 512 + tid;
        __builtin_amdgcn_global_load_lds((const GLOBAL_AS void*)(w2c + i * 8),
                                         (LDS_AS void*)(&AS[i * 8]), 16, 0, 0);
    }
    __syncthreads();

    float out_acc[4][4][4];
#pragma unroll
    for (int mi = 0; mi < 4; ++mi)
#pragma unroll
        for (int ni = 0; ni < 4; ++ni)
#pragma unroll
            for (int r = 0; r < 4; ++r) out_acc[mi][ni][r] = 0.f;

#pragma unroll 1
    for (int di = 0; di < 3; ++di) {
        const int hh  = h + di - 1;                     // per-wave row validity
        const bool hok = (hh >= 0) && (hh < H2);
        const ushort_t* SB = &SLAB[rsub + di][0];
#pragma unroll 1
        for (int dj = 0; dj < 3; ++dj) {
            const int tap = di * 3 + dj;

            float kv[4];
#pragma unroll
            for (int ni = 0; ni < 4; ++ni)
                kv[ni] = kg[(size_t)(b * H2 + h) * 1152 + tap * 128 + wn + ni * 16 + l15];

            floatx4 acc[4][4];
#pragma unroll
            for (int mi = 0; mi < 4; ++mi)
#pragma unroll
                for (int ni = 0; ni < 4; ++ni) acc[mi][ni] = (floatx4)0.f;

#pragma unroll
            for (int kc = 0; kc < 4; ++kc) {
                short8 af[4], bfr[4];
#pragma unroll
                for (int mi = 0; mi < 4; ++mi) {
                    const int row = wm + mi * 16 + l15;
                    af[mi] = *reinterpret_cast<const short8*>(
                        &AS[row * 128 + (((kc * 4 + quad) ^ (row & 7)) << 3)]);
                }
#pragma unroll
                for (int ni = 0; ni < 4; ++ni) {
                    const int col  = wn + ni * 16 + l15 + dj - 1;
                    const int colc = col & 127;
                    const short8 t = *reinterpret_cast<const short8*>(
                        &SB[colc * 128 + (((kc * 4 + quad) ^ (colc & 7)) << 3)]);
                    const bool ok = hok && (col >= 0) && (col < W2);
                    bfr[ni] = ok ? t : (short8)0;
                }
#pragma unroll
                for (int mi = 0; mi < 4; ++mi)
#pragma unroll
                    for (int ni = 0; ni < 4; ++ni)
                        acc[mi][ni] = __builtin_amdgcn_mfma_f32_16x16x32_bf16(
                            af[mi], bfr[ni], acc[mi][ni], 0, 0, 0);
            }
            // ---- scale by k_tap[w] and accumulate (adds exact 0 for edge taps)
#pragma unroll
            for (int mi = 0; mi < 4; ++mi)
#pragma unroll
                for (int ni = 0; ni < 4; ++ni)
#pragma unroll
                    for (int r = 0; r < 4; ++r)
                        out_acc[mi][ni][r] += kv[ni] * acc[mi][ni][r];

            if (tap < 8) {
                __syncthreads();                        // all AS readers done
                const ushort_t* wsrc = w2c + (size_t)(tap + 1) * 16384;
#pragma unroll
                for (int it = 0; it < 4; ++it) {
                    const int i = it * 512 + tid;
                    __builtin_amdgcn_global_load_lds((const GLOBAL_AS void*)(wsrc + i * 8),
                                                     (LDS_AS void*)(&AS[i * 8]), 16, 0, 0);
                }
                __syncthreads();                        // AS(tap+1) resident
            }
        }
    }

    // ---- final store: out NCHW fp32
#pragma unroll
    for (int mi = 0; mi < 4; ++mi)
#pragma unroll
        for (int ni = 0; ni < 4; ++ni) {
            const int w = wn + ni * 16 + l15;
#pragma unroll
            for (int r = 0; r < 4; ++r) {
                const int o = wm + mi * 16 + quad * 4 + r;
                out[(((size_t)b * C2 + o) * H2 + h) * W2 + w] = out_acc[mi][ni][r] + b2[o];
            }
        }
}

extern "C" void kernel_launch(void* const* d_in, const int* in_sizes, int n_in,
                              void* d_out, int out_size, void* d_ws, size_t ws_size,
                              hipStream_t stream) {
    const float* x     = (const float*)d_in[0];
    const float* guide = (const float*)d_in[1];
    const float* w1    = (const float*)d_in[2];
    const float* b1    = (const float*)d_in[3];
    const float* w2    = (const float*)d_in[4];
    const float* b2    = (const float*)d_in[5];
    float* out = (float*)d_out;

    ushort_t* w1c = (ushort_t*)((char*)d_ws + W1C_OFF);
    ushort_t* w2c = (ushort_t*)((char*)d_ws + W2C_OFF);
    float*    kg  = (float*)((char*)d_ws + KG_OFF);
    ushort_t* xT  = (ushort_t*)((char*)d_ws + XT_OFF);
    ushort_t* y   = (ushort_t*)((char*)d_ws + Y_OFF);

    w1c_kernel<<<W1C_ELEMS / 256, 256, 0, stream>>>(w1, w1c);
    w2c_kernel<<<W2C_ELEMS / 256, 256, 0, stream>>>(w2, w2c);
    xt_kernel<<<dim3(HH, B_), 256, 0, stream>>>(x, xT);
    k_kernel<<<dim3(H2, B_), 512, 0, stream>>>(guide, kg);
    deconv_mfma<<<dim3(64, B_), 512, 0, stream>>>(xT, w1c, b1, y);
    pac_mfma<<<dim3(64, B_), 512, 0, stream>>>(y, kg, w2c, b2, out);
}

// Round 5
// 183.324 us; speedup vs baseline: 1.6194x; 1.0052x over previous
//
#include <hip/hip_runtime.h>

#define B_  4
#define C1  256
#define C2  128
#define HH  64
#define WW  64
#define H2  128
#define W2  128

using short8  = __attribute__((ext_vector_type(8))) short;
using floatx4 = __attribute__((ext_vector_type(4))) float;
typedef unsigned short ushort_t;

#define GLOBAL_AS __attribute__((address_space(1)))
#define LDS_AS    __attribute__((address_space(3)))

// ---- workspace layout (bytes) ----
#define W1C_OFF 0u                                   // [kc4][tap4][p2][pwp2][co128][ci64] bf16, granule-swizzled
#define W1C_ELEMS (4 * 4 * 128 * 256)
#define W2C_OFF (W1C_ELEMS * 2u)                     // [tap9][o128][ci128] bf16 (granule-swizzled)
#define W2C_ELEMS (9 * 128 * 128)
#define KG_OFF  (W2C_OFF + W2C_ELEMS * 2u)           // [b][h][tap9][w128] fp32
#define KG_ELEMS (B_ * H2 * 9 * W2)
#define XT_OFF  (KG_OFF + KG_ELEMS * 4u)             // x -> [b][ih][iw][ci] bf16
#define XT_ELEMS (B_ * HH * WW * C1)
#define Y_OFF   (XT_OFF + XT_ELEMS * 2u)             // y -> [b][h][w][c] bf16, granule-swizzled by (w&7)
#define Y_ELEMS (B_ * H2 * W2 * C2)

static __device__ __forceinline__ ushort_t f2bf(float f) {
    union { float f; unsigned u; } v; v.f = f;
    unsigned r = v.u + 0x7FFFu + ((v.u >> 16) & 1u);   // RNE
    return (ushort_t)(r >> 16);
}

// ---------------------------------------------------------------------------
// Prep: w1 -> w1s[kc][tap][p][pwp][co][ci64] bf16, 16B-granule XOR-swizzled
// by (co&7) so deconv can global_load_lds it linearly and read with the XOR.
// ---------------------------------------------------------------------------
__global__ void w1c_kernel(const float* __restrict__ w1, ushort_t* __restrict__ w1c) {
    int i = blockIdx.x * 256 + threadIdx.x;
    const int sub = i & 7;
    const int gs  = (i >> 3) & 7;
    const int co  = (i >> 6) & 127;
    const int pwp = (i >> 13) & 1;
    const int p   = (i >> 14) & 1;
    const int tap = (i >> 15) & 3;
    const int kc  = (i >> 17) & 3;
    const int ci  = kc * 64 + (((gs ^ (co & 7)) << 3) | sub);
    const int kh  = p + 2 * (tap >> 1);
    const int kw  = pwp + 2 * (tap & 1);
    w1c[i] = f2bf(w1[((ci * C2 + co) * 4 + kh) * 4 + kw]);
}

// w2 -> w2c[tap][o][ci] bf16, flip baked in, 16B-granule XOR-swizzled by (o&7)
// so pac can global_load_lds it linearly and read with the XOR.
__global__ void w2c_kernel(const float* __restrict__ w2, ushort_t* __restrict__ w2c) {
    int i = blockIdx.x * 256 + threadIdx.x;
    const int ci  = i & 127;
    const int o   = (i >> 7) & 127;
    const int tap = i >> 14;
    const int fi  = 2 - tap / 3;
    const int fj  = 2 - tap % 3;
    const int gs  = ((((ci >> 3) ^ (o & 7)) << 3) | (ci & 7));
    w2c[tap * 16384 + o * 128 + gs] = f2bf(w2[((ci * C2 + o) * 3 + fi) * 3 + fj]);
}

// x (NCHW fp32) -> xT[b][ih][iw][ci] bf16 via LDS transpose
__global__ __launch_bounds__(256) void xt_kernel(const float* __restrict__ x,
                                                 ushort_t* __restrict__ xT) {
    const int ih = blockIdx.x;
    const int b  = blockIdx.y;
    const int tid = threadIdx.x;
    __shared__ ushort_t tile[64 * 72];    // [iw][cc], stride 72 (16B-aligned rows)

    for (int chunk = 0; chunk < 4; ++chunk) {
        const int ci0 = chunk * 64;
        if (chunk) __syncthreads();
#pragma unroll
        for (int it = 0; it < 16; ++it) {
            const int cc = it * 4 + (tid >> 6);
            const int iw = tid & 63;
            const float v = x[(((size_t)b * C1 + ci0 + cc) * HH + ih) * WW + iw];
            tile[iw * 72 + cc] = f2bf(v);
        }
        __syncthreads();
#pragma unroll
        for (int it = 0; it < 2; ++it) {
            const int i  = it * 256 + tid;
            const int iw = i >> 3;
            const int t  = i & 7;
            const int4 v = *reinterpret_cast<const int4*>(&tile[iw * 72 + t * 8]);
            *reinterpret_cast<int4*>(&xT[(((size_t)(b * HH + ih) * WW) + iw) * C1 + ci0 + t * 8]) = v;
        }
    }
}

// ---------------------------------------------------------------------------
// k-kernel: kg[b][h][tap][w], 512 threads = 4 c-quarters x 128 w, LDS-reduced.
// ---------------------------------------------------------------------------
__global__ __launch_bounds__(512) void k_kernel(const float* __restrict__ guide,
                                                float* __restrict__ kg) {
    const int h = blockIdx.x;
    const int b = blockIdx.y;
    const int tid = threadIdx.x;
    const int cq  = tid >> 7;
    const int n   = tid & 127;

    float acc[9];
#pragma unroll
    for (int t = 0; t < 9; ++t) acc[t] = 0.f;

    const float* gb = guide + (size_t)b * C2 * H2 * W2;
    for (int c = cq * 32; c < cq * 32 + 32; ++c) {
        const float* grow = gb + (c * H2 + h) * W2;
        const float gc = grow[n];
#pragma unroll
        for (int di = 0; di < 3; ++di) {
            const int hh = h + di - 1;
            const bool rv = (hh >= 0) && (hh < H2);
            const float* gr = gb + (c * H2 + (rv ? hh : 0)) * W2;
#pragma unroll
            for (int dj = 0; dj < 3; ++dj) {
                const int col = n + dj - 1;
                const bool cv = rv && (col >= 0) && (col < W2);
                const float gn = cv ? gr[col] : 0.f;
                const float d = gn - gc;
                acc[di * 3 + dj] += d * d;
            }
        }
    }

    __shared__ float part[4][9][128];
#pragma unroll
    for (int t = 0; t < 9; ++t) part[cq][t][n] = acc[t];
    __syncthreads();

    for (int i = tid; i < 1152; i += 512) {
        const int t  = i >> 7;
        const int nn = i & 127;
        const float s = part[0][t][nn] + part[1][t][nn] + part[2][t][nn] + part[3][t][nn];
        kg[(size_t)(b * H2 + h) * 1152 + i] = __expf(-0.5f * s);
    }
}

// ---------------------------------------------------------------------------
// Deconv MFMA v6: one 512-thread block per (b, pr) covering BOTH pwc halves.
// Output 128co x 256pix (2 oh rows x 128 ow). Grid 64x4 = 256 = 1 block/CU.
//  - B halo slab [3 ih][64 iw][256 ci] = 96 KB staged ONCE in prologue.
//  - A streamed per (kc,tap) phase via global_load_lds, double-buffered.
//  - Epilogue now writes y GRANULE-SWIZZLED by (ow&7) so pac can
//    global_load_lds slabs linearly (G21 both-sides involution).
// Same (kc,tap,k2) accumulation order as v2 -> bit-identical y.
// ---------------------------------------------------------------------------
__global__ __launch_bounds__(512, 2) void deconv_mfma(const ushort_t* __restrict__ xT,
                                                      const ushort_t* __restrict__ w1s,
                                                      const float* __restrict__ b1,
                                                      ushort_t* __restrict__ y) {
    const int pr = blockIdx.x;
    const int b  = blockIdx.y;
    const int base_oh = (pr >> 1) * 4 + (pr & 1);
    const int p    = (base_oh + 1) & 1;
    const int ihA0 = (base_oh + 1 - p) >> 1;

    const int tid  = threadIdx.x;
    const int lane = tid & 63;
    const int wave = tid >> 6;          // 0..7
    const int pwc  = wave >> 2;         // output-column parity half
    const int q    = wave & 3;          // quadrant
    const int wm   = (q & 1) * 64;
    const int wn   = (q >> 1) * 64;
    const int quad = lane >> 4;
    const int l15  = lane & 15;
    const int pwp  = 1 - pwc;

    __shared__ __align__(16) ushort_t BS[3 * 64 * 256];      // 98304 B
    __shared__ __align__(16) ushort_t AS[2][2 * 128 * 64];   // 2 x 32768 B

    // ---- prologue: issue A(phase 0) via global_load_lds (zero registers)
    {
        const ushort_t* src = w1s + (size_t)(0 * 2 + p) * 16384;
#pragma unroll
        for (int it = 0; it < 4; ++it) {
            const int i = it * 512 + tid;
            __builtin_amdgcn_global_load_lds((const GLOBAL_AS void*)(src + i * 8),
                                             (LDS_AS void*)(&AS[0][i * 8]), 16, 0, 0);
        }
    }
    // ---- stage B slab: rows ihA0-1..ihA0+1, 6144 granules, zero OOB rows
#pragma unroll
    for (int it = 0; it < 12; ++it) {
        const int i   = it * 512 + tid;      // 0..6143
        const int pix = i >> 5;              // 0..191
        const int g   = i & 31;
        const int sr  = pix >> 6;
        const int iw  = pix & 63;
        const int ih  = ihA0 - 1 + sr;
        int4 v = make_int4(0, 0, 0, 0);
        if (ih >= 0 && ih < HH)
            v = *reinterpret_cast<const int4*>(
                &xT[(((size_t)(b * HH + ih) * WW) + iw) * C1 + g * 8]);
        *reinterpret_cast<int4*>(&BS[pix * 256 + ((g ^ (pix & 7)) << 3)]) = v;
    }
    __syncthreads();

    floatx4 acc[4][4];
#pragma unroll
    for (int mi = 0; mi < 4; ++mi)
#pragma unroll
        for (int ni = 0; ni < 4; ++ni) acc[mi][ni] = (floatx4)0.f;

#pragma unroll 1
    for (int ph = 0; ph < 16; ++ph) {        // ph = kc*4 + tap (v2 order)
        const int kc  = ph >> 2;
        const int tap = ph & 3;
        const int cur = ph & 1;
        // ---- issue next A into the other buffer (flies under this GEMM)
        if (ph < 15) {
            const ushort_t* src = w1s + (size_t)((ph + 1) * 2 + p) * 16384;
#pragma unroll
            for (int it = 0; it < 4; ++it) {
                const int i = it * 512 + tid;
                __builtin_amdgcn_global_load_lds((const GLOBAL_AS void*)(src + i * 8),
                                                 (LDS_AS void*)(&AS[cur ^ 1][i * 8]), 16, 0, 0);
            }
        }
        const int th = tap >> 1, tw = tap & 1;
#pragma unroll
        for (int k2 = 0; k2 < 2; ++k2) {
            short8 af[4], bfr[4];
#pragma unroll
            for (int mi = 0; mi < 4; ++mi) {
                const int row = wm + mi * 16 + l15;
                af[mi] = *reinterpret_cast<const short8*>(
                    &AS[cur][pwp * 8192 + row * 64 + (((k2 * 4 + quad) ^ (row & 7)) << 3)]);
            }
#pragma unroll
            for (int ni = 0; ni < 4; ++ni) {
                const int n   = wn + ni * 16 + l15;
                const int rh  = n >> 6;
                const int n64 = n & 63;
                const int iw  = n64 + pwc - tw;
                const int pix = (rh - th + 1) * 64 + (iw & 63);
                const short8 t = *reinterpret_cast<const short8*>(
                    &BS[pix * 256 + kc * 64 + (((k2 * 4 + quad) ^ (pix & 7)) << 3)]);
                const bool ok = (iw >= 0) && (iw < WW);
                bfr[ni] = ok ? t : (short8)0;
            }
#pragma unroll
            for (int mi = 0; mi < 4; ++mi)
#pragma unroll
                for (int ni = 0; ni < 4; ++ni)
                    acc[mi][ni] = __builtin_amdgcn_mfma_f32_16x16x32_bf16(
                        af[mi], bfr[ni], acc[mi][ni], 0, 0, 0);
        }
        __syncthreads();   // AS[cur] readers done; AS[cur^1] resident (vmcnt drain)
    }

    // ---- epilogue: transpose in LDS (reuse BS) -> y[b][oh][ow][swz(co)] bf16
    ushort_t* Ot = BS;                       // [256 pix][128 co], stride 136
#pragma unroll
    for (int mi = 0; mi < 4; ++mi)
#pragma unroll
        for (int ni = 0; ni < 4; ++ni) {
            const int n = wn + ni * 16 + l15;
#pragma unroll
            for (int r = 0; r < 4; ++r) {
                const int co = wm + mi * 16 + quad * 4 + r;
                Ot[(pwc * 128 + n) * 136 + co] = f2bf(acc[mi][ni][r] + b1[co]);
            }
        }
    __syncthreads();
#pragma unroll
    for (int it = 0; it < 8; ++it) {
        const int i    = it * 512 + tid;
        const int n_   = i >> 4;             // 0..255
        const int t    = i & 15;
        const int half = n_ >> 7;
        const int n    = n_ & 127;
        const int rh   = n >> 6;
        const int n64  = n & 63;
        const int oh   = base_oh + 2 * rh;
        const int ow   = 2 * n64 + half;
        const int4 v = *reinterpret_cast<const int4*>(&Ot[n_ * 136 + t * 8]);
        *reinterpret_cast<int4*>(
            &y[(((size_t)(b * H2 + oh) * W2) + ow) * C2 + ((t ^ (ow & 7)) << 3)]) = v;
    }
}

// ---------------------------------------------------------------------------
// PAC MFMA v7: one 512-thread block per (b, 2 output rows). Grid 64x4 = 256
// = 1 block/CU. LDS = 3 rotating y-slabs (96 KB) + AS[2] (64 KB) = 160 KiB.
//  - ALL staging is zero-register global_load_lds (y is pre-swizzled by the
//    deconv epilogue; w2c pre-swizzled by prep). Linear DMA dest, XOR on read.
//  - AS double-buffered: AS[tap+1] issued BEFORE tap's GEMM -> L2 latency
//    hidden under MFMA; ONE barrier per tap (10 total vs v5's 17).
//  - Slab s3 (row h0+2, needed only at di=2) streams into buffer 0 during
//    di=1 (its readers finished at the di=0 end barrier).
//  - Edge taps zero-predicated at fragment read -> bit-identical to v5.
// ---------------------------------------------------------------------------
__global__ __launch_bounds__(512, 2) void pac_mfma(const ushort_t* __restrict__ y,
                                                   const float* __restrict__ kg,
                                                   const ushort_t* __restrict__ w2c,
                                                   const float* __restrict__ b2,
                                                   float* __restrict__ out) {
    const int hblk = blockIdx.x;
    const int b    = blockIdx.y;
    const int h0   = hblk * 2;

    const int tid  = threadIdx.x;
    const int lane = tid & 63;
    const int wave = tid >> 6;          // 0..7
    const int rsub = wave >> 2;         // which of the 2 output rows
    const int q    = wave & 3;          // quadrant
    const int wm   = (q & 1) * 64;
    const int wn   = (q >> 1) * 64;
    const int quad = lane >> 4;
    const int l15  = lane & 15;
    const int h    = h0 + rsub;

    __shared__ __align__(16) ushort_t SLAB[3][128 * 128];  // rotating y rows
    __shared__ __align__(16) ushort_t AS[2][128 * 128];    // w2c double buffer

    // ---- prologue: issue AS[0] (tap0) + slabs s=0,1,2 (all linear DMA)
#pragma unroll
    for (int it = 0; it < 4; ++it) {
        const int i = it * 512 + tid;
        __builtin_amdgcn_global_load_lds((const GLOBAL_AS void*)(w2c + i * 8),
                                         (LDS_AS void*)(&AS[0][i * 8]), 16, 0, 0);
    }
#pragma unroll 1
    for (int s = 0; s < 3; ++s) {
        const int hh = h0 - 1 + s;
        if (hh < 0) continue;                          // block-uniform (s=0 @ h0==0)
        const ushort_t* ysrc = y + (size_t)(b * H2 + hh) * W2 * C2;
#pragma unroll
        for (int it = 0; it < 4; ++it) {
            const int i = it * 512 + tid;
            __builtin_amdgcn_global_load_lds((const GLOBAL_AS void*)(ysrc + i * 8),
                                             (LDS_AS void*)(&SLAB[s][i * 8]), 16, 0, 0);
        }
    }
    __syncthreads();

    float out_acc[4][4][4];
#pragma unroll
    for (int mi = 0; mi < 4; ++mi)
#pragma unroll
        for (int ni = 0; ni < 4; ++ni)
#pragma unroll
            for (int r = 0; r < 4; ++r) out_acc[mi][ni][r] = 0.f;

#pragma unroll 1
    for (int di = 0; di < 3; ++di) {
        // ---- stream slab s3 (row h0+2) into buffer 0 during di=1:
        // buffer 0's readers (di=0) finished at the di=0 end barrier.
        if (di == 1 && h0 + 2 < H2) {
            const ushort_t* ysrc = y + (size_t)(b * H2 + h0 + 2) * W2 * C2;
#pragma unroll
            for (int it = 0; it < 4; ++it) {
                const int i = it * 512 + tid;
                __builtin_amdgcn_global_load_lds((const GLOBAL_AS void*)(ysrc + i * 8),
                                                 (LDS_AS void*)(&SLAB[0][i * 8]), 16, 0, 0);
            }
        }
        const int hh  = h + di - 1;                     // per-wave row validity
        const bool hok = (hh >= 0) && (hh < H2);
        const ushort_t* SB = &SLAB[(rsub + di) % 3][0];
#pragma unroll 1
        for (int dj = 0; dj < 3; ++dj) {
            const int tap = di * 3 + dj;
            // ---- issue AS[tap+1] into the other buffer (flies under GEMM)
            if (tap < 8) {
                const ushort_t* wsrc = w2c + (size_t)(tap + 1) * 16384;
#pragma unroll
                for (int it = 0; it < 4; ++it) {
                    const int i = it * 512 + tid;
                    __builtin_amdgcn_global_load_lds((const GLOBAL_AS void*)(wsrc + i * 8),
                                                     (LDS_AS void*)(&AS[(tap + 1) & 1][i * 8]),
                                                     16, 0, 0);
                }
            }

            float kv[4];
#pragma unroll
            for (int ni = 0; ni < 4; ++ni)
                kv[ni] = kg[(size_t)(b * H2 + h) * 1152 + tap * 128 + wn + ni * 16 + l15];

            floatx4 acc[4][4];
#pragma unroll
            for (int mi = 0; mi < 4; ++mi)
#pragma unroll
                for (int ni = 0; ni < 4; ++ni) acc[mi][ni] = (floatx4)0.f;

            const ushort_t* AScur = &AS[tap & 1][0];
#pragma unroll
            for (int kc = 0; kc < 4; ++kc) {
                short8 af[4], bfr[4];
#pragma unroll
                for (int mi = 0; mi < 4; ++mi) {
                    const int row = wm + mi * 16 + l15;
                    af[mi] = *reinterpret_cast<const short8*>(
                        &AScur[row * 128 + (((kc * 4 + quad) ^ (row & 7)) << 3)]);
                }
#pragma unroll
                for (int ni = 0; ni < 4; ++ni) {
                    const int col  = wn + ni * 16 + l15 + dj - 1;
                    const int colc = col & 127;
                    const short8 t = *reinterpret_cast<const short8*>(
                        &SB[colc * 128 + (((kc * 4 + quad) ^ (colc & 7)) << 3)]);
                    const bool ok = hok && (col >= 0) && (col < W2);
                    bfr[ni] = ok ? t : (short8)0;
                }
#pragma unroll
                for (int mi = 0; mi < 4; ++mi)
#pragma unroll
                    for (int ni = 0; ni < 4; ++ni)
                        acc[mi][ni] = __builtin_amdgcn_mfma_f32_16x16x32_bf16(
                            af[mi], bfr[ni], acc[mi][ni], 0, 0, 0);
            }
            // ---- scale by k_tap[w] and accumulate (adds exact 0 for edge taps)
#pragma unroll
            for (int mi = 0; mi < 4; ++mi)
#pragma unroll
                for (int ni = 0; ni < 4; ++ni)
#pragma unroll
                    for (int r = 0; r < 4; ++r)
                        out_acc[mi][ni][r] += kv[ni] * acc[mi][ni][r];

            __syncthreads();   // AS[tap&1] readers done; AS[(tap+1)&1] resident
        }
    }

    // ---- final store: out NCHW fp32
#pragma unroll
    for (int mi = 0; mi < 4; ++mi)
#pragma unroll
        for (int ni = 0; ni < 4; ++ni) {
            const int w = wn + ni * 16 + l15;
#pragma unroll
            for (int r = 0; r < 4; ++r) {
                const int o = wm + mi * 16 + quad * 4 + r;
                out[(((size_t)b * C2 + o) * H2 + h) * W2 + w] = out_acc[mi][ni][r] + b2[o];
            }
        }
}

extern "C" void kernel_launch(void* const* d_in, const int* in_sizes, int n_in,
                              void* d_out, int out_size, void* d_ws, size_t ws_size,
                              hipStream_t stream) {
    const float* x     = (const float*)d_in[0];
    const float* guide = (const float*)d_in[1];
    const float* w1    = (const float*)d_in[2];
    const float* b1    = (const float*)d_in[3];
    const float* w2    = (const float*)d_in[4];
    const float* b2    = (const float*)d_in[5];
    float* out = (float*)d_out;

    ushort_t* w1c = (ushort_t*)((char*)d_ws + W1C_OFF);
    ushort_t* w2c = (ushort_t*)((char*)d_ws + W2C_OFF);
    float*    kg  = (float*)((char*)d_ws + KG_OFF);
    ushort_t* xT  = (ushort_t*)((char*)d_ws + XT_OFF);
    ushort_t* y   = (ushort_t*)((char*)d_ws + Y_OFF);

    w1c_kernel<<<W1C_ELEMS / 256, 256, 0, stream>>>(w1, w1c);
    w2c_kernel<<<W2C_ELEMS / 256, 256, 0, stream>>>(w2, w2c);
    xt_kernel<<<dim3(HH, B_), 256, 0, stream>>>(x, xT);
    k_kernel<<<dim3(H2, B_), 512, 0, stream>>>(guide, kg);
    deconv_mfma<<<dim3(64, B_), 512, 0, stream>>>(xT, w1c, b1, y);
    pac_mfma<<<dim3(64, B_), 512, 0, stream>>>(y, kg, w2c, b2, out);
}

// Round 6
// 172.945 us; speedup vs baseline: 1.7166x; 1.0600x over previous
//
#include <hip/hip_runtime.h>

#define B_  4
#define C1  256
#define C2  128
#define HH  64
#define WW  64
#define H2  128
#define W2  128

using short8  = __attribute__((ext_vector_type(8))) short;
using floatx4 = __attribute__((ext_vector_type(4))) float;
typedef unsigned short ushort_t;

#define GLOBAL_AS __attribute__((address_space(1)))
#define LDS_AS    __attribute__((address_space(3)))

// ---- workspace layout (bytes) ----
#define W1C_OFF 0u                                   // [kc4][tap4][p2][pwp2][co128][ci64] bf16, granule-swizzled
#define W1C_ELEMS (4 * 4 * 128 * 256)
#define W2C_OFF (W1C_ELEMS * 2u)                     // [tap9][o128][ci128] bf16 (granule-swizzled)
#define W2C_ELEMS (9 * 128 * 128)
#define KG_OFF  (W2C_OFF + W2C_ELEMS * 2u)           // [b][h][tap9][w128] fp32
#define KG_ELEMS (B_ * H2 * 9 * W2)
#define XT_OFF  (KG_OFF + KG_ELEMS * 4u)             // x -> [b][ih][iw][ci] bf16
#define XT_ELEMS (B_ * HH * WW * C1)
#define Y_OFF   (XT_OFF + XT_ELEMS * 2u)             // y -> [b][h][w][c] bf16, granule-swizzled by (w&7)
#define Y_ELEMS (B_ * H2 * W2 * C2)

// prep_kernel section boundaries (blocks of 512 threads)
#define PREP_W1C_BLKS (W1C_ELEMS / 512)              // 1024
#define PREP_W2C_BLKS (W2C_ELEMS / 512)              // 288
#define PREP_XT_BLKS  (B_ * HH)                      // 256
#define PREP_K_BLKS   (B_ * H2)                      // 512
#define PREP_B0 PREP_W1C_BLKS
#define PREP_B1 (PREP_B0 + PREP_W2C_BLKS)
#define PREP_B2 (PREP_B1 + PREP_XT_BLKS)
#define PREP_B3 (PREP_B2 + PREP_K_BLKS)              // 2080 total

static __device__ __forceinline__ ushort_t f2bf(float f) {
    union { float f; unsigned u; } v; v.f = f;
    unsigned r = v.u + 0x7FFFu + ((v.u >> 16) & 1u);   // RNE
    return (ushort_t)(r >> 16);
}

// ---------------------------------------------------------------------------
// Fused prep: 4 independent sections co-scheduled in ONE launch.
//  sec 0: w1 -> w1s[kc][tap][p][pwp][co][ci64], granule-swizzled by (co&7)
//  sec 1: w2 -> w2c[tap][o][ci], flip baked, granule-swizzled by (o&7)
//  sec 2: x (NCHW fp32) -> xT[b][ih][iw][ci] bf16 (LDS transpose)
//  sec 3: kg[b][h][tap][w] guide kernel (identical math to standalone k)
// ---------------------------------------------------------------------------
__global__ __launch_bounds__(512) void prep_kernel(const float* __restrict__ w1,
                                                   ushort_t* __restrict__ w1c,
                                                   const float* __restrict__ w2,
                                                   ushort_t* __restrict__ w2c,
                                                   const float* __restrict__ x,
                                                   ushort_t* __restrict__ xT,
                                                   const float* __restrict__ guide,
                                                   float* __restrict__ kg) {
    const int bid = blockIdx.x;
    const int tid = threadIdx.x;
    __shared__ __align__(16) char smem[18432];       // max(tile 17408, part 18432)

    if (bid < PREP_B0) {
        // ---- w1 prep (same per-element math as before, 512-thr mapping)
        const int i   = bid * 512 + tid;
        const int sub = i & 7;
        const int gs  = (i >> 3) & 7;
        const int co  = (i >> 6) & 127;
        const int pwp = (i >> 13) & 1;
        const int p   = (i >> 14) & 1;
        const int tap = (i >> 15) & 3;
        const int kc  = (i >> 17) & 3;
        const int ci  = kc * 64 + (((gs ^ (co & 7)) << 3) | sub);
        const int kh  = p + 2 * (tap >> 1);
        const int kw  = pwp + 2 * (tap & 1);
        w1c[i] = f2bf(w1[((ci * C2 + co) * 4 + kh) * 4 + kw]);
    } else if (bid < PREP_B1) {
        // ---- w2 prep
        const int i   = (bid - PREP_B0) * 512 + tid;
        const int ci  = i & 127;
        const int o   = (i >> 7) & 127;
        const int tap = i >> 14;
        const int fi  = 2 - tap / 3;
        const int fj  = 2 - tap % 3;
        const int gs  = ((((ci >> 3) ^ (o & 7)) << 3) | (ci & 7));
        w2c[tap * 16384 + o * 128 + gs] = f2bf(w2[((ci * C2 + o) * 3 + fi) * 3 + fj]);
    } else if (bid < PREP_B2) {
        // ---- x transpose: (b, ih) per block, 2 chunks of 128 ci
        const int idx = bid - PREP_B1;
        const int ih  = idx & 63;
        const int b   = idx >> 6;
        ushort_t* tile = (ushort_t*)smem;            // [iw][cc], stride 136
        for (int chunk = 0; chunk < 2; ++chunk) {
            const int ci0 = chunk * 128;
            if (chunk) __syncthreads();
#pragma unroll
            for (int it = 0; it < 16; ++it) {
                const int cc = it * 8 + (tid >> 6);
                const int iw = tid & 63;
                const float v = x[(((size_t)b * C1 + ci0 + cc) * HH + ih) * WW + iw];
                tile[iw * 136 + cc] = f2bf(v);
            }
            __syncthreads();
#pragma unroll
            for (int it = 0; it < 2; ++it) {
                const int i  = it * 512 + tid;
                const int iw = i >> 4;
                const int t  = i & 15;
                const int4 v = *reinterpret_cast<const int4*>(&tile[iw * 136 + t * 8]);
                *reinterpret_cast<int4*>(
                    &xT[(((size_t)(b * HH + ih) * WW) + iw) * C1 + ci0 + t * 8]) = v;
            }
        }
    } else {
        // ---- guide kernel k (identical math/order to standalone version)
        const int idx = bid - PREP_B2;
        const int h   = idx & 127;
        const int b   = idx >> 7;
        const int cq  = tid >> 7;
        const int n   = tid & 127;

        float acc[9];
#pragma unroll
        for (int t = 0; t < 9; ++t) acc[t] = 0.f;

        const float* gb = guide + (size_t)b * C2 * H2 * W2;
        for (int c = cq * 32; c < cq * 32 + 32; ++c) {
            const float* grow = gb + (c * H2 + h) * W2;
            const float gc = grow[n];
#pragma unroll
            for (int di = 0; di < 3; ++di) {
                const int hh = h + di - 1;
                const bool rv = (hh >= 0) && (hh < H2);
                const float* gr = gb + (c * H2 + (rv ? hh : 0)) * W2;
#pragma unroll
                for (int dj = 0; dj < 3; ++dj) {
                    const int col = n + dj - 1;
                    const bool cv = rv && (col >= 0) && (col < W2);
                    const float gn = cv ? gr[col] : 0.f;
                    const float d = gn - gc;
                    acc[di * 3 + dj] += d * d;
                }
            }
        }

        float (*part)[9][128] = (float (*)[9][128])smem;
#pragma unroll
        for (int t = 0; t < 9; ++t) part[cq][t][n] = acc[t];
        __syncthreads();

        for (int i = tid; i < 1152; i += 512) {
            const int t  = i >> 7;
            const int nn = i & 127;
            const float s = part[0][t][nn] + part[1][t][nn] + part[2][t][nn] + part[3][t][nn];
            kg[(size_t)(b * H2 + h) * 1152 + i] = __expf(-0.5f * s);
        }
    }
}

// ---------------------------------------------------------------------------
// Deconv MFMA v6 + XCD swizzle: one 512-thread block per (b, pr), both pwc
// halves. Output 128co x 256pix. Grid 64x4 = 256 = 1 block/CU.
// ---------------------------------------------------------------------------
__global__ __launch_bounds__(512, 2) void deconv_mfma(const ushort_t* __restrict__ xT,
                                                      const ushort_t* __restrict__ w1s,
                                                      const float* __restrict__ b1,
                                                      ushort_t* __restrict__ y) {
    const int bx = blockIdx.x;
    const int pr = ((bx & 7) << 3) | (bx >> 3);      // XCD-contiguous pr ranges
    const int b  = blockIdx.y;
    const int base_oh = (pr >> 1) * 4 + (pr & 1);
    const int p    = (base_oh + 1) & 1;
    const int ihA0 = (base_oh + 1 - p) >> 1;

    const int tid  = threadIdx.x;
    const int lane = tid & 63;
    const int wave = tid >> 6;          // 0..7
    const int pwc  = wave >> 2;         // output-column parity half
    const int q    = wave & 3;          // quadrant
    const int wm   = (q & 1) * 64;
    const int wn   = (q >> 1) * 64;
    const int quad = lane >> 4;
    const int l15  = lane & 15;
    const int pwp  = 1 - pwc;

    __shared__ __align__(16) ushort_t BS[3 * 64 * 256];      // 98304 B
    __shared__ __align__(16) ushort_t AS[2][2 * 128 * 64];   // 2 x 32768 B

    // ---- prologue: issue A(phase 0) via global_load_lds (zero registers)
    {
        const ushort_t* src = w1s + (size_t)(0 * 2 + p) * 16384;
#pragma unroll
        for (int it = 0; it < 4; ++it) {
            const int i = it * 512 + tid;
            __builtin_amdgcn_global_load_lds((const GLOBAL_AS void*)(src + i * 8),
                                             (LDS_AS void*)(&AS[0][i * 8]), 16, 0, 0);
        }
    }
    // ---- stage B slab: rows ihA0-1..ihA0+1, 6144 granules, zero OOB rows
#pragma unroll
    for (int it = 0; it < 12; ++it) {
        const int i   = it * 512 + tid;      // 0..6143
        const int pix = i >> 5;              // 0..191
        const int g   = i & 31;
        const int sr  = pix >> 6;
        const int iw  = pix & 63;
        const int ih  = ihA0 - 1 + sr;
        int4 v = make_int4(0, 0, 0, 0);
        if (ih >= 0 && ih < HH)
            v = *reinterpret_cast<const int4*>(
                &xT[(((size_t)(b * HH + ih) * WW) + iw) * C1 + g * 8]);
        *reinterpret_cast<int4*>(&BS[pix * 256 + ((g ^ (pix & 7)) << 3)]) = v;
    }
    __syncthreads();

    floatx4 acc[4][4];
#pragma unroll
    for (int mi = 0; mi < 4; ++mi)
#pragma unroll
        for (int ni = 0; ni < 4; ++ni) acc[mi][ni] = (floatx4)0.f;

#pragma unroll 1
    for (int ph = 0; ph < 16; ++ph) {        // ph = kc*4 + tap (v2 order)
        const int kc  = ph >> 2;
        const int tap = ph & 3;
        const int cur = ph & 1;
        // ---- issue next A into the other buffer (flies under this GEMM)
        if (ph < 15) {
            const ushort_t* src = w1s + (size_t)((ph + 1) * 2 + p) * 16384;
#pragma unroll
            for (int it = 0; it < 4; ++it) {
                const int i = it * 512 + tid;
                __builtin_amdgcn_global_load_lds((const GLOBAL_AS void*)(src + i * 8),
                                                 (LDS_AS void*)(&AS[cur ^ 1][i * 8]), 16, 0, 0);
            }
        }
        const int th = tap >> 1, tw = tap & 1;
#pragma unroll
        for (int k2 = 0; k2 < 2; ++k2) {
            short8 af[4], bfr[4];
#pragma unroll
            for (int mi = 0; mi < 4; ++mi) {
                const int row = wm + mi * 16 + l15;
                af[mi] = *reinterpret_cast<const short8*>(
                    &AS[cur][pwp * 8192 + row * 64 + (((k2 * 4 + quad) ^ (row & 7)) << 3)]);
            }
#pragma unroll
            for (int ni = 0; ni < 4; ++ni) {
                const int n   = wn + ni * 16 + l15;
                const int rh  = n >> 6;
                const int n64 = n & 63;
                const int iw  = n64 + pwc - tw;
                const int pix = (rh - th + 1) * 64 + (iw & 63);
                const short8 t = *reinterpret_cast<const short8*>(
                    &BS[pix * 256 + kc * 64 + (((k2 * 4 + quad) ^ (pix & 7)) << 3)]);
                const bool ok = (iw >= 0) && (iw < WW);
                bfr[ni] = ok ? t : (short8)0;
            }
#pragma unroll
            for (int mi = 0; mi < 4; ++mi)
#pragma unroll
                for (int ni = 0; ni < 4; ++ni)
                    acc[mi][ni] = __builtin_amdgcn_mfma_f32_16x16x32_bf16(
                        af[mi], bfr[ni], acc[mi][ni], 0, 0, 0);
        }
        __syncthreads();   // AS[cur] readers done; AS[cur^1] resident (vmcnt drain)
    }

    // ---- epilogue: transpose in LDS (reuse BS) -> y[b][oh][ow][swz(co)] bf16
    ushort_t* Ot = BS;                       // [256 pix][128 co], stride 136
#pragma unroll
    for (int mi = 0; mi < 4; ++mi)
#pragma unroll
        for (int ni = 0; ni < 4; ++ni) {
            const int n = wn + ni * 16 + l15;
#pragma unroll
            for (int r = 0; r < 4; ++r) {
                const int co = wm + mi * 16 + quad * 4 + r;
                Ot[(pwc * 128 + n) * 136 + co] = f2bf(acc[mi][ni][r] + b1[co]);
            }
        }
    __syncthreads();
#pragma unroll
    for (int it = 0; it < 8; ++it) {
        const int i    = it * 512 + tid;
        const int n_   = i >> 4;             // 0..255
        const int t    = i & 15;
        const int half = n_ >> 7;
        const int n    = n_ & 127;
        const int rh   = n >> 6;
        const int n64  = n & 63;
        const int oh   = base_oh + 2 * rh;
        const int ow   = 2 * n64 + half;
        const int4 v = *reinterpret_cast<const int4*>(&Ot[n_ * 136 + t * 8]);
        *reinterpret_cast<int4*>(
            &y[(((size_t)(b * H2 + oh) * W2) + ow) * C2 + ((t ^ (ow & 7)) << 3)]) = v;
    }
}

// ---------------------------------------------------------------------------
// PAC MFMA v7 + XCD swizzle: one 512-thread block per (b, 2 output rows).
// Grid 64x4 = 256 = 1 block/CU. LDS = 3 y-slabs + AS[2] = 160 KiB.
// ---------------------------------------------------------------------------
__global__ __launch_bounds__(512, 2) void pac_mfma(const ushort_t* __restrict__ y,
                                                   const float* __restrict__ kg,
                                                   const ushort_t* __restrict__ w2c,
                                                   const float* __restrict__ b2,
                                                   float* __restrict__ out) {
    const int bx   = blockIdx.x;
    const int hblk = ((bx & 7) << 3) | (bx >> 3);    // XCD-contiguous h ranges
    const int b    = blockIdx.y;
    const int h0   = hblk * 2;

    const int tid  = threadIdx.x;
    const int lane = tid & 63;
    const int wave = tid >> 6;          // 0..7
    const int rsub = wave >> 2;         // which of the 2 output rows
    const int q    = wave & 3;          // quadrant
    const int wm   = (q & 1) * 64;
    const int wn   = (q >> 1) * 64;
    const int quad = lane >> 4;
    const int l15  = lane & 15;
    const int h    = h0 + rsub;

    __shared__ __align__(16) ushort_t SLAB[3][128 * 128];  // rotating y rows
    __shared__ __align__(16) ushort_t AS[2][128 * 128];    // w2c double buffer

    // ---- prologue: issue AS[0] (tap0) + slabs s=0,1,2 (all linear DMA)
#pragma unroll
    for (int it = 0; it < 4; ++it) {
        const int i = it * 512 + tid;
        __builtin_amdgcn_global_load_lds((const GLOBAL_AS void*)(w2c + i * 8),
                                         (LDS_AS void*)(&AS[0][i * 8]), 16, 0, 0);
    }
#pragma unroll 1
    for (int s = 0; s < 3; ++s) {
        const int hh = h0 - 1 + s;
        if (hh < 0) continue;                          // block-uniform (s=0 @ h0==0)
        const ushort_t* ysrc = y + (size_t)(b * H2 + hh) * W2 * C2;
#pragma unroll
        for (int it = 0; it < 4; ++it) {
            const int i = it * 512 + tid;
            __builtin_amdgcn_global_load_lds((const GLOBAL_AS void*)(ysrc + i * 8),
                                             (LDS_AS void*)(&SLAB[s][i * 8]), 16, 0, 0);
        }
    }
    __syncthreads();

    float out_acc[4][4][4];
#pragma unroll
    for (int mi = 0; mi < 4; ++mi)
#pragma unroll
        for (int ni = 0; ni < 4; ++ni)
#pragma unroll
            for (int r = 0; r < 4; ++r) out_acc[mi][ni][r] = 0.f;

#pragma unroll 1
    for (int di = 0; di < 3; ++di) {
        // ---- stream slab s3 (row h0+2) into buffer 0 during di=1:
        // buffer 0's readers (di=0) finished at the di=0 end barrier.
        if (di == 1 && h0 + 2 < H2) {
            const ushort_t* ysrc = y + (size_t)(b * H2 + h0 + 2) * W2 * C2;
#pragma unroll
            for (int it = 0; it < 4; ++it) {
                const int i = it * 512 + tid;
                __builtin_amdgcn_global_load_lds((const GLOBAL_AS void*)(ysrc + i * 8),
                                                 (LDS_AS void*)(&SLAB[0][i * 8]), 16, 0, 0);
            }
        }
        const int hh  = h + di - 1;                     // per-wave row validity
        const bool hok = (hh >= 0) && (hh < H2);
        const ushort_t* SB = &SLAB[(rsub + di) % 3][0];
#pragma unroll 1
        for (int dj = 0; dj < 3; ++dj) {
            const int tap = di * 3 + dj;
            // ---- issue AS[tap+1] into the other buffer (flies under GEMM)
            if (tap < 8) {
                const ushort_t* wsrc = w2c + (size_t)(tap + 1) * 16384;
#pragma unroll
                for (int it = 0; it < 4; ++it) {
                    const int i = it * 512 + tid;
                    __builtin_amdgcn_global_load_lds((const GLOBAL_AS void*)(wsrc + i * 8),
                                                     (LDS_AS void*)(&AS[(tap + 1) & 1][i * 8]),
                                                     16, 0, 0);
                }
            }

            float kv[4];
#pragma unroll
            for (int ni = 0; ni < 4; ++ni)
                kv[ni] = kg[(size_t)(b * H2 + h) * 1152 + tap * 128 + wn + ni * 16 + l15];

            floatx4 acc[4][4];
#pragma unroll
            for (int mi = 0; mi < 4; ++mi)
#pragma unroll
                for (int ni = 0; ni < 4; ++ni) acc[mi][ni] = (floatx4)0.f;

            const ushort_t* AScur = &AS[tap & 1][0];
#pragma unroll
            for (int kc = 0; kc < 4; ++kc) {
                short8 af[4], bfr[4];
#pragma unroll
                for (int mi = 0; mi < 4; ++mi) {
                    const int row = wm + mi * 16 + l15;
                    af[mi] = *reinterpret_cast<const short8*>(
                        &AScur[row * 128 + (((kc * 4 + quad) ^ (row & 7)) << 3)]);
                }
#pragma unroll
                for (int ni = 0; ni < 4; ++ni) {
                    const int col  = wn + ni * 16 + l15 + dj - 1;
                    const int colc = col & 127;
                    const short8 t = *reinterpret_cast<const short8*>(
                        &SB[colc * 128 + (((kc * 4 + quad) ^ (colc & 7)) << 3)]);
                    const bool ok = hok && (col >= 0) && (col < W2);
                    bfr[ni] = ok ? t : (short8)0;
                }
#pragma unroll
                for (int mi = 0; mi < 4; ++mi)
#pragma unroll
                    for (int ni = 0; ni < 4; ++ni)
                        acc[mi][ni] = __builtin_amdgcn_mfma_f32_16x16x32_bf16(
                            af[mi], bfr[ni], acc[mi][ni], 0, 0, 0);
            }
            // ---- scale by k_tap[w] and accumulate (adds exact 0 for edge taps)
#pragma unroll
            for (int mi = 0; mi < 4; ++mi)
#pragma unroll
                for (int ni = 0; ni < 4; ++ni)
#pragma unroll
                    for (int r = 0; r < 4; ++r)
                        out_acc[mi][ni][r] += kv[ni] * acc[mi][ni][r];

            __syncthreads();   // AS[tap&1] readers done; AS[(tap+1)&1] resident
        }
    }

    // ---- final store: out NCHW fp32
#pragma unroll
    for (int mi = 0; mi < 4; ++mi)
#pragma unroll
        for (int ni = 0; ni < 4; ++ni) {
            const int w = wn + ni * 16 + l15;
#pragma unroll
            for (int r = 0; r < 4; ++r) {
                const int o = wm + mi * 16 + quad * 4 + r;
                out[(((size_t)b * C2 + o) * H2 + h) * W2 + w] = out_acc[mi][ni][r] + b2[o];
            }
        }
}

extern "C" void kernel_launch(void* const* d_in, const int* in_sizes, int n_in,
                              void* d_out, int out_size, void* d_ws, size_t ws_size,
                              hipStream_t stream) {
    const float* x     = (const float*)d_in[0];
    const float* guide = (const float*)d_in[1];
    const float* w1    = (const float*)d_in[2];
    const float* b1    = (const float*)d_in[3];
    const float* w2    = (const float*)d_in[4];
    const float* b2    = (const float*)d_in[5];
    float* out = (float*)d_out;

    ushort_t* w1c = (ushort_t*)((char*)d_ws + W1C_OFF);
    ushort_t* w2c = (ushort_t*)((char*)d_ws + W2C_OFF);
    float*    kg  = (float*)((char*)d_ws + KG_OFF);
    ushort_t* xT  = (ushort_t*)((char*)d_ws + XT_OFF);
    ushort_t* y   = (ushort_t*)((char*)d_ws + Y_OFF);

    prep_kernel<<<PREP_B3, 512, 0, stream>>>(w1, w1c, w2, w2c, x, xT, guide, kg);
    deconv_mfma<<<dim3(64, B_), 512, 0, stream>>>(xT, w1c, b1, y);
    pac_mfma<<<dim3(64, B_), 512, 0, stream>>>(y, kg, w2c, b2, out);
}